// Round 1
// baseline (3652.035 us; speedup 1.0000x reference)
//
#include <hip/hip_runtime.h>
#include <cstdint>
#include <cstddef>

#define EMB 128
#define NLIG 32768
#define NREC 262144
#define NGRAPH 1024
#define ELIG 327680
#define EREC 2097152
#define BN_EPS 1e-5f

// ============================ CSR build ============================

__global__ __launch_bounds__(256)
void gk_count(const int* __restrict__ dst, int* __restrict__ cnt, int E) {
  int e = blockIdx.x * 256 + threadIdx.x;
  if (e < E) atomicAdd(&cnt[dst[e]], 1);
}

// block scans 1024 elements (256 threads x 4); writes per-element exclusive
// prefix (within block) to off[], block total to bsum[blockIdx.x]
__global__ __launch_bounds__(256)
void gk_scan1(const int* __restrict__ cnt, int* __restrict__ off,
              int* __restrict__ bsum, int n) {
  __shared__ int sm[256];
  int t = threadIdx.x;
  int base = blockIdx.x * 1024 + t * 4;
  int v0 = (base + 0 < n) ? cnt[base + 0] : 0;
  int v1 = (base + 1 < n) ? cnt[base + 1] : 0;
  int v2 = (base + 2 < n) ? cnt[base + 2] : 0;
  int v3 = (base + 3 < n) ? cnt[base + 3] : 0;
  int loc = v0 + v1 + v2 + v3;
  sm[t] = loc;
  __syncthreads();
  for (int o = 1; o < 256; o <<= 1) {
    int x = (t >= o) ? sm[t - o] : 0;
    __syncthreads();
    sm[t] += x;
    __syncthreads();
  }
  int run = sm[t] - loc;  // exclusive prefix for this thread
  if (base + 0 < n) off[base + 0] = run;
  run += v0;
  if (base + 1 < n) off[base + 1] = run;
  run += v1;
  if (base + 2 < n) off[base + 2] = run;
  run += v2;
  if (base + 3 < n) off[base + 3] = run;
  if (t == 255) bsum[blockIdx.x] = sm[255];
}

// exclusive scan of bsum[nb], nb <= 256, single block
__global__ __launch_bounds__(256)
void gk_scan2(int* __restrict__ bsum, int nb) {
  __shared__ int sm[256];
  int t = threadIdx.x;
  int v = (t < nb) ? bsum[t] : 0;
  sm[t] = v;
  __syncthreads();
  for (int o = 1; o < 256; o <<= 1) {
    int x = (t >= o) ? sm[t - o] : 0;
    __syncthreads();
    sm[t] += x;
    __syncthreads();
  }
  if (t < nb) bsum[t] = sm[t] - v;  // exclusive
}

__global__ __launch_bounds__(256)
void gk_scan3(int* __restrict__ off, const int* __restrict__ bsum, int n, int E) {
  int i = blockIdx.x * 256 + threadIdx.x;
  if (i < n) off[i] += bsum[i >> 10];
  if (i == 0) off[n] = E;
}

__global__ __launch_bounds__(256)
void gk_copy(int* __restrict__ d, const int* __restrict__ s, int n) {
  int i = blockIdx.x * 256 + threadIdx.x;
  if (i < n) d[i] = s[i];
}

__global__ __launch_bounds__(256)
void gk_fill(const int* __restrict__ src, const int* __restrict__ dst,
             int* __restrict__ cur, int* __restrict__ csr, int E) {
  int e = blockIdx.x * 256 + threadIdx.x;
  if (e < E) {
    int d = dst[e];
    int pos = atomicAdd(&cur[d], 1);
    csr[pos] = src[e];
  }
}

__global__ __launch_bounds__(256)
void gk_dinv(const int* __restrict__ off, float* __restrict__ dinv, int n) {
  int i = blockIdx.x * 256 + threadIdx.x;
  if (i < n) dinv[i] = rsqrtf((float)(off[i + 1] - off[i] + 1));
}

// ============================ encoders ============================

__global__ __launch_bounds__(128)
void gk_ligenc(const int* __restrict__ lig_x, const int* __restrict__ offs,
               const float* __restrict__ emb, float* __restrict__ A) {
  __shared__ int idx[9];
  int i = blockIdx.x;
  int c = threadIdx.x;
  if (c < 9) idx[c] = lig_x[i * 9 + c] + offs[c];
  __syncthreads();
  float acc = 0.f;
#pragma unroll
  for (int f = 0; f < 9; ++f) acc += emb[(size_t)idx[f] * EMB + c];
  A[(size_t)i * EMB + c] = acc;
}

// rec encoder: A = rec_x_float[262144,199] @ rec_w[199,128] + rec_emb1[xi] + rec_b
// 32 rows/block, 256 threads = 128 channels x 2 row-groups of 16
__global__ __launch_bounds__(256)
void gk_recenc(const float* __restrict__ X, const int* __restrict__ xi,
               const float* __restrict__ emb1, const float* __restrict__ W,
               const float* __restrict__ b, float* __restrict__ A) {
  __shared__ float Wl[128 * 68];  // W^T chunk, stride 68
  __shared__ float xs[32 * 68];   // x chunk
  const int K = 199;
  int t = threadIdx.x;
  int row0 = blockIdx.x * 32;
  int c = t & 127, grp = t >> 7;
  int rbase = grp * 16;
  float acc[16];
#pragma unroll
  for (int r = 0; r < 16; ++r) acc[r] = 0.f;

  for (int kc = 0; kc < K; kc += 64) {
    int klen = K - kc; if (klen > 64) klen = 64;
    int kpad = (klen + 3) & ~3;            // 64 or 8
    int kshift = (kpad == 64) ? 6 : 3;
    // stage W^T (pad zeros)
    for (int idx2 = t; idx2 < 128 * kpad; idx2 += 256) {
      int dk = idx2 >> 7, cc = idx2 & 127;
      float v = (kc + dk < K) ? W[(size_t)(kc + dk) * 128 + cc] : 0.f;
      Wl[cc * 68 + dk] = v;
    }
    // stage x rows (pad zeros)
    for (int idx2 = t; idx2 < 32 * kpad; idx2 += 256) {
      int r = idx2 >> kshift, dk = idx2 & (kpad - 1);
      int k = kc + dk;
      float v = (k < K) ? X[(size_t)(row0 + r) * K + k] : 0.f;
      xs[r * 68 + dk] = v;
    }
    __syncthreads();
    for (int dk = 0; dk < kpad; dk += 4) {
      float4 w4 = *(const float4*)&Wl[c * 68 + dk];
#pragma unroll
      for (int r = 0; r < 16; ++r) {
        float4 x4 = *(const float4*)&xs[(rbase + r) * 68 + dk];
        acc[r] += w4.x * x4.x + w4.y * x4.y + w4.z * x4.z + w4.w * x4.w;
      }
    }
    __syncthreads();
  }
#pragma unroll
  for (int r = 0; r < 16; ++r) {
    int row = row0 + rbase + r;
    float v = acc[r] + b[c] + emb1[(size_t)xi[row] * EMB + c];
    A[(size_t)row * EMB + c] = v;
  }
}

// ============================ GCN layer ============================

// g = (bn_relu?(X) @ W) * dinv[row]   ; BN+ReLU of the PREVIOUS layer is
// fused into the LDS staging of X (donorm=1 for layers >= 1).
__global__ __launch_bounds__(256)
void gk_gcn_gemm(const float* __restrict__ X, const float* __restrict__ W,
                 const float* __restrict__ stats, const float* __restrict__ gamma,
                 const float* __restrict__ beta, float inv_n, int donorm,
                 const float* __restrict__ dinv, float* __restrict__ out) {
  __shared__ float Wl[128 * 68];
  __shared__ float xs[32 * 68];
  int t = threadIdx.x;
  int row0 = blockIdx.x * 32;
  int c = t & 127, grp = t >> 7;
  int rbase = grp * 16;
  float acc[16];
#pragma unroll
  for (int r = 0; r < 16; ++r) acc[r] = 0.f;

  for (int kc = 0; kc < 128; kc += 64) {
    for (int idx2 = t; idx2 < 128 * 64; idx2 += 256) {
      int dk = idx2 >> 7, cc = idx2 & 127;
      Wl[cc * 68 + dk] = W[(size_t)(kc + dk) * 128 + cc];
    }
    for (int idx2 = t; idx2 < 32 * 64; idx2 += 256) {
      int r = idx2 >> 6, dk = idx2 & 63;
      int k = kc + dk;
      float v = X[(size_t)(row0 + r) * 128 + k];
      if (donorm) {
        float mu = stats[k] * inv_n;
        float var = stats[128 + k] * inv_n - mu * mu;
        float scl = gamma[k] * rsqrtf(var + BN_EPS);
        v = (v - mu) * scl + beta[k];
        v = v > 0.f ? v : 0.f;
      }
      xs[r * 68 + dk] = v;
    }
    __syncthreads();
    for (int dk = 0; dk < 64; dk += 4) {
      float4 w4 = *(const float4*)&Wl[c * 68 + dk];
#pragma unroll
      for (int r = 0; r < 16; ++r) {
        float4 x4 = *(const float4*)&xs[(rbase + r) * 68 + dk];
        acc[r] += w4.x * x4.x + w4.y * x4.y + w4.z * x4.z + w4.w * x4.w;
      }
    }
    __syncthreads();
  }
#pragma unroll
  for (int r = 0; r < 16; ++r) {
    int row = row0 + rbase + r;
    out[(size_t)row * 128 + c] = acc[r] * dinv[row];
  }
}

// out[i] = dinv[i]*(g[i] + sum_{e in CSR[i]} g[src_e])   (pre-BN; bias b
// cancels in BN so it is dropped).  Also accumulates per-channel BN stats.
__global__ __launch_bounds__(128)
void gk_agg(const float* __restrict__ g, const int* __restrict__ off,
            const int* __restrict__ csr, const float* __restrict__ dinv,
            float* __restrict__ outb, float* __restrict__ stats) {
  int c = threadIdx.x;
  int i0 = blockIdx.x * 32;
  float s = 0.f, ss = 0.f;
  for (int i = i0; i < i0 + 32; ++i) {
    int e0 = off[i], e1 = off[i + 1];
    float acc = g[(size_t)i * 128 + c];
    for (int e = e0; e < e1; ++e) {
      int src = csr[e];
      acc += g[(size_t)src * 128 + c];
    }
    acc *= dinv[i];
    outb[(size_t)i * 128 + c] = acc;
    s += acc;
    ss += acc * acc;
  }
  atomicAdd(&stats[c], s);
  atomicAdd(&stats[c + 128], ss);
}

// per-graph mean of relu(bn(A)) for the last layer; contiguous batch blocks
__global__ __launch_bounds__(128)
void gk_pool(const float* __restrict__ A, const float* __restrict__ stats,
             const float* __restrict__ gamma, const float* __restrict__ beta,
             float inv_n, float* __restrict__ z, int npg, int zoff) {
  int gidx = blockIdx.x;
  int c = threadIdx.x;
  float mu = stats[c] * inv_n;
  float var = stats[128 + c] * inv_n - mu * mu;
  float scl = gamma[c] * rsqrtf(var + BN_EPS);
  float be = beta[c];
  float sum = 0.f;
  int r0 = gidx * npg;
  for (int r = 0; r < npg; ++r) {
    float v = (A[(size_t)(r0 + r) * 128 + c] - mu) * scl + be;
    sum += v > 0.f ? v : 0.f;
  }
  z[(size_t)gidx * 256 + zoff + c] = sum * (1.0f / (float)npg);
}

// final MLP: out[g] = relu(z @ w1 + b1) @ w2 + b2
__global__ __launch_bounds__(128)
void gk_mlp(const float* __restrict__ z, const float* __restrict__ w1,
            const float* __restrict__ b1, const float* __restrict__ w2,
            const float* __restrict__ b2, float* __restrict__ out) {
  __shared__ float zs[256];
  __shared__ float red[128];
  int gidx = blockIdx.x, t = threadIdx.x;
  zs[t] = z[(size_t)gidx * 256 + t];
  zs[t + 128] = z[(size_t)gidx * 256 + 128 + t];
  __syncthreads();
  float acc = b1[t];
  for (int k = 0; k < 256; ++k) acc += zs[k] * w1[(size_t)k * 128 + t];
  acc = (acc > 0.f ? acc : 0.f) * w2[t];
  red[t] = acc;
  __syncthreads();
  for (int o = 64; o > 0; o >>= 1) {
    if (t < o) red[t] += red[t + o];
    __syncthreads();
  }
  if (t == 0) out[gidx] = red[0] + b2[0];
}

// ============================ launch ============================

extern "C" void kernel_launch(void* const* d_in, const int* in_sizes, int n_in,
                              void* d_out, int out_size, void* d_ws, size_t ws_size,
                              hipStream_t stream) {
  (void)in_sizes; (void)n_in; (void)out_size; (void)ws_size;
  const int*   lig_x       = (const int*)  d_in[0];
  const int*   rec_x_int   = (const int*)  d_in[1];
  const float* rec_x_float = (const float*)d_in[2];
  const int*   lig_ei      = (const int*)  d_in[3];
  const int*   rec_ei      = (const int*)  d_in[4];
  const int*   atom_off    = (const int*)  d_in[7];
  const float* atom_emb    = (const float*)d_in[8];
  const float* rec_emb1    = (const float*)d_in[9];
  const float* rec_w       = (const float*)d_in[10];
  const float* rec_b       = (const float*)d_in[11];
  const float* lig_W       = (const float*)d_in[12];
  // d_in[13] lig_b: cancels in BN
  const float* lig_gamma   = (const float*)d_in[14];
  const float* lig_beta    = (const float*)d_in[15];
  const float* rec_W       = (const float*)d_in[16];
  // d_in[17] rec_bc: cancels in BN
  const float* rec_gamma   = (const float*)d_in[18];
  const float* rec_beta    = (const float*)d_in[19];
  const float* out_w1      = (const float*)d_in[20];
  const float* out_b1      = (const float*)d_in[21];
  const float* out_w2      = (const float*)d_in[22];
  const float* out_b2      = (const float*)d_in[23];
  float* out = (float*)d_out;

  char* p = (char*)d_ws;
  auto alloc = [&](size_t bytes) -> void* {
    void* r = p;
    p += (bytes + 255) & ~(size_t)255;
    return r;
  };
  float* A        = (float*)alloc((size_t)NREC * EMB * 4);  // features (in/out ping)
  float* B        = (float*)alloc((size_t)NREC * EMB * 4);  // g = (A@W)*dinv
  float* dinv_lig = (float*)alloc((size_t)NLIG * 4);
  float* dinv_rec = (float*)alloc((size_t)NREC * 4);
  int*   cnt_lig  = (int*)  alloc((size_t)NLIG * 4);        // later: fill cursor
  int*   cnt_rec  = (int*)  alloc((size_t)NREC * 4);
  int*   off_lig  = (int*)  alloc((size_t)(NLIG + 1) * 4);
  int*   off_rec  = (int*)  alloc((size_t)(NREC + 1) * 4);
  int*   csr_lig  = (int*)  alloc((size_t)ELIG * 4);
  int*   csr_rec  = (int*)  alloc((size_t)EREC * 4);
  int*   bsum_lig = (int*)  alloc(256 * 4);
  int*   bsum_rec = (int*)  alloc(256 * 4);
  float* stats    = (float*)alloc(256 * 4);
  float* z        = (float*)alloc((size_t)NGRAPH * 256 * 4);

  // ---- CSR build (both graph types) ----
  hipMemsetAsync(cnt_lig, 0, (size_t)NLIG * 4, stream);
  hipMemsetAsync(cnt_rec, 0, (size_t)NREC * 4, stream);
  gk_count<<<ELIG / 256, 256, 0, stream>>>(lig_ei + ELIG, cnt_lig, ELIG);
  gk_count<<<EREC / 256, 256, 0, stream>>>(rec_ei + EREC, cnt_rec, EREC);
  gk_scan1<<<NLIG / 1024, 256, 0, stream>>>(cnt_lig, off_lig, bsum_lig, NLIG);
  gk_scan2<<<1, 256, 0, stream>>>(bsum_lig, NLIG / 1024);
  gk_scan3<<<NLIG / 256, 256, 0, stream>>>(off_lig, bsum_lig, NLIG, ELIG);
  gk_scan1<<<NREC / 1024, 256, 0, stream>>>(cnt_rec, off_rec, bsum_rec, NREC);
  gk_scan2<<<1, 256, 0, stream>>>(bsum_rec, NREC / 1024);
  gk_scan3<<<NREC / 256, 256, 0, stream>>>(off_rec, bsum_rec, NREC, EREC);
  gk_copy<<<NLIG / 256, 256, 0, stream>>>(cnt_lig, off_lig, NLIG);  // cursor
  gk_copy<<<NREC / 256, 256, 0, stream>>>(cnt_rec, off_rec, NREC);
  gk_fill<<<ELIG / 256, 256, 0, stream>>>(lig_ei, lig_ei + ELIG, cnt_lig, csr_lig, ELIG);
  gk_fill<<<EREC / 256, 256, 0, stream>>>(rec_ei, rec_ei + EREC, cnt_rec, csr_rec, EREC);
  gk_dinv<<<NLIG / 256, 256, 0, stream>>>(off_lig, dinv_lig, NLIG);
  gk_dinv<<<NREC / 256, 256, 0, stream>>>(off_rec, dinv_rec, NREC);

  auto run_entity = [&](const float* Wall, const float* gamma, const float* beta,
                        const int* offv, const int* csrv, const float* dinv,
                        int n, int npg, int zoff) {
    float inv_n = 1.0f / (float)n;
    for (int l = 0; l < 3; ++l) {
      const float* W = Wall + (size_t)l * EMB * EMB;
      const float* gm = (l > 0) ? gamma + (size_t)(l - 1) * EMB : gamma;
      const float* bt = (l > 0) ? beta + (size_t)(l - 1) * EMB : beta;
      gk_gcn_gemm<<<n / 32, 256, 0, stream>>>(A, W, stats, gm, bt, inv_n,
                                              l > 0 ? 1 : 0, dinv, B);
      hipMemsetAsync(stats, 0, 256 * 4, stream);
      gk_agg<<<n / 32, 128, 0, stream>>>(B, offv, csrv, dinv, A, stats);
    }
    gk_pool<<<NGRAPH, 128, 0, stream>>>(A, stats, gamma + 2 * EMB, beta + 2 * EMB,
                                        inv_n, z, npg, zoff);
  };

  // ---- ligand path ----
  gk_ligenc<<<NLIG, 128, 0, stream>>>(lig_x, atom_off, atom_emb, A);
  run_entity(lig_W, lig_gamma, lig_beta, off_lig, csr_lig, dinv_lig,
             NLIG, NLIG / NGRAPH, 0);

  // ---- receptor path ----
  gk_recenc<<<NREC / 32, 256, 0, stream>>>(rec_x_float, rec_x_int, rec_emb1,
                                           rec_w, rec_b, A);
  run_entity(rec_W, rec_gamma, rec_beta, off_rec, csr_rec, dinv_rec,
             NREC, NREC / NGRAPH, EMB);

  // ---- head ----
  gk_mlp<<<NGRAPH, 128, 0, stream>>>(z, out_w1, out_b1, out_w2, out_b2, out);
}

// Round 2
// 3052.130 us; speedup vs baseline: 1.1966x; 1.1966x over previous
//
#include <hip/hip_runtime.h>
#include <cstdint>
#include <cstddef>

#define EMB 128
#define NLIG 32768
#define NREC 262144
#define NGRAPH 1024
#define ELIG 327680
#define EREC 2097152
#define BN_EPS 1e-5f

// ============================ CSR build ============================

__global__ __launch_bounds__(256)
void gk_count(const int* __restrict__ dst, int* __restrict__ cnt, int E) {
  int e = blockIdx.x * 256 + threadIdx.x;
  if (e < E) atomicAdd(&cnt[dst[e]], 1);
}

__global__ __launch_bounds__(256)
void gk_scan1(const int* __restrict__ cnt, int* __restrict__ off,
              int* __restrict__ bsum, int n) {
  __shared__ int sm[256];
  int t = threadIdx.x;
  int base = blockIdx.x * 1024 + t * 4;
  int v0 = (base + 0 < n) ? cnt[base + 0] : 0;
  int v1 = (base + 1 < n) ? cnt[base + 1] : 0;
  int v2 = (base + 2 < n) ? cnt[base + 2] : 0;
  int v3 = (base + 3 < n) ? cnt[base + 3] : 0;
  int loc = v0 + v1 + v2 + v3;
  sm[t] = loc;
  __syncthreads();
  for (int o = 1; o < 256; o <<= 1) {
    int x = (t >= o) ? sm[t - o] : 0;
    __syncthreads();
    sm[t] += x;
    __syncthreads();
  }
  int run = sm[t] - loc;
  if (base + 0 < n) off[base + 0] = run;
  run += v0;
  if (base + 1 < n) off[base + 1] = run;
  run += v1;
  if (base + 2 < n) off[base + 2] = run;
  run += v2;
  if (base + 3 < n) off[base + 3] = run;
  if (t == 255) bsum[blockIdx.x] = sm[255];
}

__global__ __launch_bounds__(256)
void gk_scan2(int* __restrict__ bsum, int nb) {
  __shared__ int sm[256];
  int t = threadIdx.x;
  int v = (t < nb) ? bsum[t] : 0;
  sm[t] = v;
  __syncthreads();
  for (int o = 1; o < 256; o <<= 1) {
    int x = (t >= o) ? sm[t - o] : 0;
    __syncthreads();
    sm[t] += x;
    __syncthreads();
  }
  if (t < nb) bsum[t] = sm[t] - v;
}

__global__ __launch_bounds__(256)
void gk_scan3(int* __restrict__ off, const int* __restrict__ bsum, int n, int E) {
  int i = blockIdx.x * 256 + threadIdx.x;
  if (i < n) off[i] += bsum[i >> 10];
  if (i == 0) off[n] = E;
}

__global__ __launch_bounds__(256)
void gk_copy(int* __restrict__ d, const int* __restrict__ s, int n) {
  int i = blockIdx.x * 256 + threadIdx.x;
  if (i < n) d[i] = s[i];
}

__global__ __launch_bounds__(256)
void gk_fill(const int* __restrict__ src, const int* __restrict__ dst,
             int* __restrict__ cur, int* __restrict__ csr, int E) {
  int e = blockIdx.x * 256 + threadIdx.x;
  if (e < E) {
    int d = dst[e];
    int pos = atomicAdd(&cur[d], 1);
    csr[pos] = src[e];
  }
}

__global__ __launch_bounds__(256)
void gk_dinv(const int* __restrict__ off, float* __restrict__ dinv, int n) {
  int i = blockIdx.x * 256 + threadIdx.x;
  if (i < n) dinv[i] = rsqrtf((float)(off[i + 1] - off[i] + 1));
}

// ============================ encoders ============================

__global__ __launch_bounds__(128)
void gk_ligenc(const int* __restrict__ lig_x, const int* __restrict__ offs,
               const float* __restrict__ emb, float* __restrict__ A) {
  __shared__ int idx[9];
  int i = blockIdx.x;
  int c = threadIdx.x;
  if (c < 9) idx[c] = lig_x[i * 9 + c] + offs[c];
  __syncthreads();
  float acc = 0.f;
#pragma unroll
  for (int f = 0; f < 9; ++f) acc += emb[(size_t)idx[f] * EMB + c];
  A[(size_t)i * EMB + c] = acc;
}

// rec encoder: A = X[262144,199] @ W[199,128] + emb1[xi] + b
// 64 rows x 128 ch per block; per-thread 8 rows x 4 ch.
// Wl in [k][c] layout (lane-consecutive float4 reads); Xt transposed [k][row]
// (broadcast reads).
__global__ __launch_bounds__(256)
void gk_recenc(const float* __restrict__ X, const int* __restrict__ xi,
               const float* __restrict__ emb1, const float* __restrict__ W,
               const float* __restrict__ b, float* __restrict__ A) {
  __shared__ float Wl[32 * 128];
  __shared__ float Xt[32 * 68];
  const int K = 199;
  int t = threadIdx.x;
  int row0 = blockIdx.x * 64;
  int cg = t & 31, rg = t >> 5;
  int c0 = cg * 4, r0 = rg * 8;
  float4 acc[8];
#pragma unroll
  for (int j = 0; j < 8; ++j) acc[j] = make_float4(0.f, 0.f, 0.f, 0.f);

  for (int kc = 0; kc < K; kc += 32) {
    // stage W rows kc..kc+31 (zero-pad past K)
    for (int i = t; i < 1024; i += 256) {  // 1024 float4
      int kk = i >> 5;
      float4 v = make_float4(0.f, 0.f, 0.f, 0.f);
      if (kc + kk < K) v = ((const float4*)(W + (size_t)(kc + kk) * 128))[i & 31];
      ((float4*)Wl)[i] = v;
    }
    // stage X transposed (scalar loads; X row stride 199 is odd)
    for (int i = t; i < 512; i += 256) {
      int r = i >> 3, q = i & 7;
      int kb = kc + q * 4;
      const float* xr = X + (size_t)(row0 + r) * K;
      float v0 = (kb + 0 < K) ? xr[kb + 0] : 0.f;
      float v1 = (kb + 1 < K) ? xr[kb + 1] : 0.f;
      float v2 = (kb + 2 < K) ? xr[kb + 2] : 0.f;
      float v3 = (kb + 3 < K) ? xr[kb + 3] : 0.f;
      Xt[(q * 4 + 0) * 68 + r] = v0;
      Xt[(q * 4 + 1) * 68 + r] = v1;
      Xt[(q * 4 + 2) * 68 + r] = v2;
      Xt[(q * 4 + 3) * 68 + r] = v3;
    }
    __syncthreads();
#pragma unroll
    for (int k = 0; k < 32; ++k) {
      float4 w = *(const float4*)&Wl[k * 128 + c0];
      float4 xa = *(const float4*)&Xt[k * 68 + r0];
      float4 xb = *(const float4*)&Xt[k * 68 + r0 + 4];
#pragma unroll
      for (int j = 0; j < 4; ++j) {
        float xv = (&xa.x)[j];
        acc[j].x = fmaf(xv, w.x, acc[j].x);
        acc[j].y = fmaf(xv, w.y, acc[j].y);
        acc[j].z = fmaf(xv, w.z, acc[j].z);
        acc[j].w = fmaf(xv, w.w, acc[j].w);
      }
#pragma unroll
      for (int j = 0; j < 4; ++j) {
        float xv = (&xb.x)[j];
        acc[4 + j].x = fmaf(xv, w.x, acc[4 + j].x);
        acc[4 + j].y = fmaf(xv, w.y, acc[4 + j].y);
        acc[4 + j].z = fmaf(xv, w.z, acc[4 + j].z);
        acc[4 + j].w = fmaf(xv, w.w, acc[4 + j].w);
      }
    }
    __syncthreads();
  }
  float4 b4 = *(const float4*)(b + c0);
#pragma unroll
  for (int j = 0; j < 8; ++j) {
    int row = row0 + r0 + j;
    float4 e = *(const float4*)(emb1 + (size_t)xi[row] * 128 + c0);
    float4 o;
    o.x = acc[j].x + b4.x + e.x;
    o.y = acc[j].y + b4.y + e.y;
    o.z = acc[j].z + b4.z + e.z;
    o.w = acc[j].w + b4.w + e.w;
    *(float4*)(A + (size_t)row * 128 + c0) = o;
  }
}

// ============================ GCN layer ============================

// g = (bn_relu?(X) @ W) * dinv[row] ; BN+ReLU of previous layer fused into
// LDS staging (coeffs precomputed per block). Same tiling as gk_recenc.
__global__ __launch_bounds__(256)
void gk_gcn_gemm(const float* __restrict__ X, const float* __restrict__ W,
                 const float* __restrict__ stats, const float* __restrict__ gamma,
                 const float* __restrict__ beta, float inv_n, int donorm,
                 const float* __restrict__ dinv, float* __restrict__ out) {
  __shared__ float Wl[32 * 128];
  __shared__ float Xt[32 * 68];
  __shared__ float bnscl[128];
  __shared__ float bnsh[128];
  int t = threadIdx.x;
  int row0 = blockIdx.x * 64;
  int cg = t & 31, rg = t >> 5;
  int c0 = cg * 4, r0 = rg * 8;

  if (t < 128) {
    if (donorm) {
      float mu = stats[t] * inv_n;
      float var = stats[128 + t] * inv_n - mu * mu;
      float s = gamma[t] * rsqrtf(var + BN_EPS);
      bnscl[t] = s;
      bnsh[t] = beta[t] - mu * s;
    } else {
      bnscl[t] = 1.f;
      bnsh[t] = 0.f;
    }
  }
  __syncthreads();

  float4 acc[8];
#pragma unroll
  for (int j = 0; j < 8; ++j) acc[j] = make_float4(0.f, 0.f, 0.f, 0.f);

  for (int kc = 0; kc < 128; kc += 32) {
    for (int i = t; i < 1024; i += 256) {
      ((float4*)Wl)[i] = ((const float4*)(W + (size_t)kc * 128))[i];
    }
    for (int i = t; i < 512; i += 256) {
      int r = i >> 3, q = i & 7;
      int kb = kc + q * 4;
      float4 v = *(const float4*)(X + (size_t)(row0 + r) * 128 + kb);
      if (donorm) {
        v.x = fmaf(v.x, bnscl[kb + 0], bnsh[kb + 0]);
        v.y = fmaf(v.y, bnscl[kb + 1], bnsh[kb + 1]);
        v.z = fmaf(v.z, bnscl[kb + 2], bnsh[kb + 2]);
        v.w = fmaf(v.w, bnscl[kb + 3], bnsh[kb + 3]);
        v.x = v.x > 0.f ? v.x : 0.f;
        v.y = v.y > 0.f ? v.y : 0.f;
        v.z = v.z > 0.f ? v.z : 0.f;
        v.w = v.w > 0.f ? v.w : 0.f;
      }
      Xt[(q * 4 + 0) * 68 + r] = v.x;
      Xt[(q * 4 + 1) * 68 + r] = v.y;
      Xt[(q * 4 + 2) * 68 + r] = v.z;
      Xt[(q * 4 + 3) * 68 + r] = v.w;
    }
    __syncthreads();
#pragma unroll
    for (int k = 0; k < 32; ++k) {
      float4 w = *(const float4*)&Wl[k * 128 + c0];
      float4 xa = *(const float4*)&Xt[k * 68 + r0];
      float4 xb = *(const float4*)&Xt[k * 68 + r0 + 4];
#pragma unroll
      for (int j = 0; j < 4; ++j) {
        float xv = (&xa.x)[j];
        acc[j].x = fmaf(xv, w.x, acc[j].x);
        acc[j].y = fmaf(xv, w.y, acc[j].y);
        acc[j].z = fmaf(xv, w.z, acc[j].z);
        acc[j].w = fmaf(xv, w.w, acc[j].w);
      }
#pragma unroll
      for (int j = 0; j < 4; ++j) {
        float xv = (&xb.x)[j];
        acc[4 + j].x = fmaf(xv, w.x, acc[4 + j].x);
        acc[4 + j].y = fmaf(xv, w.y, acc[4 + j].y);
        acc[4 + j].z = fmaf(xv, w.z, acc[4 + j].z);
        acc[4 + j].w = fmaf(xv, w.w, acc[4 + j].w);
      }
    }
    __syncthreads();
  }
#pragma unroll
  for (int j = 0; j < 8; ++j) {
    int row = row0 + r0 + j;
    float d = dinv[row];
    float4 o;
    o.x = acc[j].x * d;
    o.y = acc[j].y * d;
    o.z = acc[j].z * d;
    o.w = acc[j].w * d;
    *(float4*)(out + (size_t)row * 128 + c0) = o;
  }
}

// out[i] = dinv[i]*(g[i] + sum_{e in CSR[i]} g[src_e]) ; accumulates BN stats.
// 16 rows/block; 2-deep load pipeline on the edge gather.
__global__ __launch_bounds__(128)
void gk_agg(const float* __restrict__ g, const int* __restrict__ off,
            const int* __restrict__ csr, const float* __restrict__ dinv,
            float* __restrict__ outb, float* __restrict__ stats) {
  int c = threadIdx.x;
  int i0 = blockIdx.x * 16;
  float s = 0.f, ss = 0.f;
  for (int i = i0; i < i0 + 16; ++i) {
    int e0 = off[i], e1 = off[i + 1];
    float acc = g[(size_t)i * 128 + c];
    float vnext = (e0 < e1) ? g[(size_t)csr[e0] * 128 + c] : 0.f;
    for (int e = e0; e < e1; ++e) {
      float v = vnext;
      vnext = (e + 1 < e1) ? g[(size_t)csr[e + 1] * 128 + c] : 0.f;
      acc += v;
    }
    acc *= dinv[i];
    outb[(size_t)i * 128 + c] = acc;
    s += acc;
    ss += acc * acc;
  }
  atomicAdd(&stats[c], s);
  atomicAdd(&stats[c + 128], ss);
}

// per-graph mean of relu(bn(A)) for the last layer
__global__ __launch_bounds__(128)
void gk_pool(const float* __restrict__ A, const float* __restrict__ stats,
             const float* __restrict__ gamma, const float* __restrict__ beta,
             float inv_n, float* __restrict__ z, int npg, int zoff) {
  int gidx = blockIdx.x;
  int c = threadIdx.x;
  float mu = stats[c] * inv_n;
  float var = stats[128 + c] * inv_n - mu * mu;
  float scl = gamma[c] * rsqrtf(var + BN_EPS);
  float be = beta[c];
  float sum = 0.f;
  int r0 = gidx * npg;
  for (int r = 0; r < npg; ++r) {
    float v = (A[(size_t)(r0 + r) * 128 + c] - mu) * scl + be;
    sum += v > 0.f ? v : 0.f;
  }
  z[(size_t)gidx * 256 + zoff + c] = sum * (1.0f / (float)npg);
}

__global__ __launch_bounds__(128)
void gk_mlp(const float* __restrict__ z, const float* __restrict__ w1,
            const float* __restrict__ b1, const float* __restrict__ w2,
            const float* __restrict__ b2, float* __restrict__ out) {
  __shared__ float zs[256];
  __shared__ float red[128];
  int gidx = blockIdx.x, t = threadIdx.x;
  zs[t] = z[(size_t)gidx * 256 + t];
  zs[t + 128] = z[(size_t)gidx * 256 + 128 + t];
  __syncthreads();
  float acc = b1[t];
  for (int k = 0; k < 256; ++k) acc += zs[k] * w1[(size_t)k * 128 + t];
  acc = (acc > 0.f ? acc : 0.f) * w2[t];
  red[t] = acc;
  __syncthreads();
  for (int o = 64; o > 0; o >>= 1) {
    if (t < o) red[t] += red[t + o];
    __syncthreads();
  }
  if (t == 0) out[gidx] = red[0] + b2[0];
}

// ============================ launch ============================

extern "C" void kernel_launch(void* const* d_in, const int* in_sizes, int n_in,
                              void* d_out, int out_size, void* d_ws, size_t ws_size,
                              hipStream_t stream) {
  (void)in_sizes; (void)n_in; (void)out_size; (void)ws_size;
  const int*   lig_x       = (const int*)  d_in[0];
  const int*   rec_x_int   = (const int*)  d_in[1];
  const float* rec_x_float = (const float*)d_in[2];
  const int*   lig_ei      = (const int*)  d_in[3];
  const int*   rec_ei      = (const int*)  d_in[4];
  const int*   atom_off    = (const int*)  d_in[7];
  const float* atom_emb    = (const float*)d_in[8];
  const float* rec_emb1    = (const float*)d_in[9];
  const float* rec_w       = (const float*)d_in[10];
  const float* rec_b       = (const float*)d_in[11];
  const float* lig_W       = (const float*)d_in[12];
  const float* lig_gamma   = (const float*)d_in[14];
  const float* lig_beta    = (const float*)d_in[15];
  const float* rec_W       = (const float*)d_in[16];
  const float* rec_gamma   = (const float*)d_in[18];
  const float* rec_beta    = (const float*)d_in[19];
  const float* out_w1      = (const float*)d_in[20];
  const float* out_b1      = (const float*)d_in[21];
  const float* out_w2      = (const float*)d_in[22];
  const float* out_b2      = (const float*)d_in[23];
  float* out = (float*)d_out;

  char* p = (char*)d_ws;
  auto alloc = [&](size_t bytes) -> void* {
    void* r = p;
    p += (bytes + 255) & ~(size_t)255;
    return r;
  };
  float* A        = (float*)alloc((size_t)NREC * EMB * 4);
  float* B        = (float*)alloc((size_t)NREC * EMB * 4);
  float* dinv_lig = (float*)alloc((size_t)NLIG * 4);
  float* dinv_rec = (float*)alloc((size_t)NREC * 4);
  int*   cnt_lig  = (int*)  alloc((size_t)NLIG * 4);
  int*   cnt_rec  = (int*)  alloc((size_t)NREC * 4);
  int*   off_lig  = (int*)  alloc((size_t)(NLIG + 1) * 4);
  int*   off_rec  = (int*)  alloc((size_t)(NREC + 1) * 4);
  int*   csr_lig  = (int*)  alloc((size_t)ELIG * 4);
  int*   csr_rec  = (int*)  alloc((size_t)EREC * 4);
  int*   bsum_lig = (int*)  alloc(256 * 4);
  int*   bsum_rec = (int*)  alloc(256 * 4);
  float* stats    = (float*)alloc(256 * 4);
  float* z        = (float*)alloc((size_t)NGRAPH * 256 * 4);

  // ---- CSR build ----
  hipMemsetAsync(cnt_lig, 0, (size_t)NLIG * 4, stream);
  hipMemsetAsync(cnt_rec, 0, (size_t)NREC * 4, stream);
  gk_count<<<ELIG / 256, 256, 0, stream>>>(lig_ei + ELIG, cnt_lig, ELIG);
  gk_count<<<EREC / 256, 256, 0, stream>>>(rec_ei + EREC, cnt_rec, EREC);
  gk_scan1<<<NLIG / 1024, 256, 0, stream>>>(cnt_lig, off_lig, bsum_lig, NLIG);
  gk_scan2<<<1, 256, 0, stream>>>(bsum_lig, NLIG / 1024);
  gk_scan3<<<NLIG / 256, 256, 0, stream>>>(off_lig, bsum_lig, NLIG, ELIG);
  gk_scan1<<<NREC / 1024, 256, 0, stream>>>(cnt_rec, off_rec, bsum_rec, NREC);
  gk_scan2<<<1, 256, 0, stream>>>(bsum_rec, NREC / 1024);
  gk_scan3<<<NREC / 256, 256, 0, stream>>>(off_rec, bsum_rec, NREC, EREC);
  gk_copy<<<NLIG / 256, 256, 0, stream>>>(cnt_lig, off_lig, NLIG);
  gk_copy<<<NREC / 256, 256, 0, stream>>>(cnt_rec, off_rec, NREC);
  gk_fill<<<ELIG / 256, 256, 0, stream>>>(lig_ei, lig_ei + ELIG, cnt_lig, csr_lig, ELIG);
  gk_fill<<<EREC / 256, 256, 0, stream>>>(rec_ei, rec_ei + EREC, cnt_rec, csr_rec, EREC);
  gk_dinv<<<NLIG / 256, 256, 0, stream>>>(off_lig, dinv_lig, NLIG);
  gk_dinv<<<NREC / 256, 256, 0, stream>>>(off_rec, dinv_rec, NREC);

  auto run_entity = [&](const float* Wall, const float* gamma, const float* beta,
                        const int* offv, const int* csrv, const float* dinv,
                        int n, int npg, int zoff) {
    float inv_n = 1.0f / (float)n;
    for (int l = 0; l < 3; ++l) {
      const float* W = Wall + (size_t)l * EMB * EMB;
      const float* gm = (l > 0) ? gamma + (size_t)(l - 1) * EMB : gamma;
      const float* bt = (l > 0) ? beta + (size_t)(l - 1) * EMB : beta;
      gk_gcn_gemm<<<n / 64, 256, 0, stream>>>(A, W, stats, gm, bt, inv_n,
                                              l > 0 ? 1 : 0, dinv, B);
      hipMemsetAsync(stats, 0, 256 * 4, stream);
      gk_agg<<<n / 16, 128, 0, stream>>>(B, offv, csrv, dinv, A, stats);
    }
    gk_pool<<<NGRAPH, 128, 0, stream>>>(A, stats, gamma + 2 * EMB, beta + 2 * EMB,
                                        inv_n, z, npg, zoff);
  };

  // ---- ligand path ----
  gk_ligenc<<<NLIG, 128, 0, stream>>>(lig_x, atom_off, atom_emb, A);
  run_entity(lig_W, lig_gamma, lig_beta, off_lig, csr_lig, dinv_lig,
             NLIG, NLIG / NGRAPH, 0);

  // ---- receptor path ----
  gk_recenc<<<NREC / 64, 256, 0, stream>>>(rec_x_float, rec_x_int, rec_emb1,
                                           rec_w, rec_b, A);
  run_entity(rec_W, rec_gamma, rec_beta, off_rec, csr_rec, dinv_rec,
             NREC, NREC / NGRAPH, EMB);

  // ---- head ----
  gk_mlp<<<NGRAPH, 128, 0, stream>>>(z, out_w1, out_b1, out_w2, out_b2, out);
}

// Round 3
// 2547.067 us; speedup vs baseline: 1.4338x; 1.1983x over previous
//
#include <hip/hip_runtime.h>
#include <cstdint>
#include <cstddef>

#define EMB 128
#define NLIG 32768
#define NREC 262144
#define NGRAPH 1024
#define ELIG 327680
#define EREC 2097152
#define BN_EPS 1e-5f

// ============================ CSR build ============================

__global__ __launch_bounds__(256)
void gk_count(const int* __restrict__ dst, int* __restrict__ cnt, int E) {
  int e = blockIdx.x * 256 + threadIdx.x;
  if (e < E) atomicAdd(&cnt[dst[e]], 1);
}

__global__ __launch_bounds__(256)
void gk_scan1(const int* __restrict__ cnt, int* __restrict__ off,
              int* __restrict__ bsum, int n) {
  __shared__ int sm[256];
  int t = threadIdx.x;
  int base = blockIdx.x * 1024 + t * 4;
  int v0 = (base + 0 < n) ? cnt[base + 0] : 0;
  int v1 = (base + 1 < n) ? cnt[base + 1] : 0;
  int v2 = (base + 2 < n) ? cnt[base + 2] : 0;
  int v3 = (base + 3 < n) ? cnt[base + 3] : 0;
  int loc = v0 + v1 + v2 + v3;
  sm[t] = loc;
  __syncthreads();
  for (int o = 1; o < 256; o <<= 1) {
    int x = (t >= o) ? sm[t - o] : 0;
    __syncthreads();
    sm[t] += x;
    __syncthreads();
  }
  int run = sm[t] - loc;
  if (base + 0 < n) off[base + 0] = run;
  run += v0;
  if (base + 1 < n) off[base + 1] = run;
  run += v1;
  if (base + 2 < n) off[base + 2] = run;
  run += v2;
  if (base + 3 < n) off[base + 3] = run;
  if (t == 255) bsum[blockIdx.x] = sm[255];
}

__global__ __launch_bounds__(256)
void gk_scan2(int* __restrict__ bsum, int nb) {
  __shared__ int sm[256];
  int t = threadIdx.x;
  int v = (t < nb) ? bsum[t] : 0;
  sm[t] = v;
  __syncthreads();
  for (int o = 1; o < 256; o <<= 1) {
    int x = (t >= o) ? sm[t - o] : 0;
    __syncthreads();
    sm[t] += x;
    __syncthreads();
  }
  if (t < nb) bsum[t] = sm[t] - v;
}

__global__ __launch_bounds__(256)
void gk_scan3(int* __restrict__ off, const int* __restrict__ bsum, int n, int E) {
  int i = blockIdx.x * 256 + threadIdx.x;
  if (i < n) off[i] += bsum[i >> 10];
  if (i == 0) off[n] = E;
}

__global__ __launch_bounds__(256)
void gk_copy(int* __restrict__ d, const int* __restrict__ s, int n) {
  int i = blockIdx.x * 256 + threadIdx.x;
  if (i < n) d[i] = s[i];
}

__global__ __launch_bounds__(256)
void gk_fill(const int* __restrict__ src, const int* __restrict__ dst,
             int* __restrict__ cur, int* __restrict__ csr, int E) {
  int e = blockIdx.x * 256 + threadIdx.x;
  if (e < E) {
    int d = dst[e];
    int pos = atomicAdd(&cur[d], 1);
    csr[pos] = src[e];
  }
}

__global__ __launch_bounds__(256)
void gk_dinv(const int* __restrict__ off, float* __restrict__ dinv, int n) {
  int i = blockIdx.x * 256 + threadIdx.x;
  if (i < n) dinv[i] = rsqrtf((float)(off[i + 1] - off[i] + 1));
}

// ============================ encoders ============================

__global__ __launch_bounds__(128)
void gk_ligenc(const int* __restrict__ lig_x, const int* __restrict__ offs,
               const float* __restrict__ emb, float* __restrict__ A) {
  __shared__ int idx[9];
  int i = blockIdx.x;
  int c = threadIdx.x;
  if (c < 9) idx[c] = lig_x[i * 9 + c] + offs[c];
  __syncthreads();
  float acc = 0.f;
#pragma unroll
  for (int f = 0; f < 9; ++f) acc += emb[(size_t)idx[f] * EMB + c];
  A[(size_t)i * EMB + c] = acc;
}

// rec encoder: A = X[262144,199] @ W[199,128] + emb1[xi] + b
__global__ __launch_bounds__(256)
void gk_recenc(const float* __restrict__ X, const int* __restrict__ xi,
               const float* __restrict__ emb1, const float* __restrict__ W,
               const float* __restrict__ b, float* __restrict__ A) {
  __shared__ float Wl[32 * 128];
  __shared__ float Xt[32 * 68];
  const int K = 199;
  int t = threadIdx.x;
  int row0 = blockIdx.x * 64;
  int cg = t & 31, rg = t >> 5;
  int c0 = cg * 4, r0 = rg * 8;
  float4 acc[8];
#pragma unroll
  for (int j = 0; j < 8; ++j) acc[j] = make_float4(0.f, 0.f, 0.f, 0.f);

  for (int kc = 0; kc < K; kc += 32) {
    for (int i = t; i < 1024; i += 256) {
      int kk = i >> 5;
      float4 v = make_float4(0.f, 0.f, 0.f, 0.f);
      if (kc + kk < K) v = ((const float4*)(W + (size_t)(kc + kk) * 128))[i & 31];
      ((float4*)Wl)[i] = v;
    }
    for (int i = t; i < 512; i += 256) {
      int r = i >> 3, q = i & 7;
      int kb = kc + q * 4;
      const float* xr = X + (size_t)(row0 + r) * K;
      float v0 = (kb + 0 < K) ? xr[kb + 0] : 0.f;
      float v1 = (kb + 1 < K) ? xr[kb + 1] : 0.f;
      float v2 = (kb + 2 < K) ? xr[kb + 2] : 0.f;
      float v3 = (kb + 3 < K) ? xr[kb + 3] : 0.f;
      Xt[(q * 4 + 0) * 68 + r] = v0;
      Xt[(q * 4 + 1) * 68 + r] = v1;
      Xt[(q * 4 + 2) * 68 + r] = v2;
      Xt[(q * 4 + 3) * 68 + r] = v3;
    }
    __syncthreads();
#pragma unroll
    for (int k = 0; k < 32; ++k) {
      float4 w = *(const float4*)&Wl[k * 128 + c0];
      float4 xa = *(const float4*)&Xt[k * 68 + r0];
      float4 xb = *(const float4*)&Xt[k * 68 + r0 + 4];
#pragma unroll
      for (int j = 0; j < 4; ++j) {
        float xv = (&xa.x)[j];
        acc[j].x = fmaf(xv, w.x, acc[j].x);
        acc[j].y = fmaf(xv, w.y, acc[j].y);
        acc[j].z = fmaf(xv, w.z, acc[j].z);
        acc[j].w = fmaf(xv, w.w, acc[j].w);
      }
#pragma unroll
      for (int j = 0; j < 4; ++j) {
        float xv = (&xb.x)[j];
        acc[4 + j].x = fmaf(xv, w.x, acc[4 + j].x);
        acc[4 + j].y = fmaf(xv, w.y, acc[4 + j].y);
        acc[4 + j].z = fmaf(xv, w.z, acc[4 + j].z);
        acc[4 + j].w = fmaf(xv, w.w, acc[4 + j].w);
      }
    }
    __syncthreads();
  }
  float4 b4 = *(const float4*)(b + c0);
#pragma unroll
  for (int j = 0; j < 8; ++j) {
    int row = row0 + r0 + j;
    float4 e = *(const float4*)(emb1 + (size_t)xi[row] * 128 + c0);
    float4 o;
    o.x = acc[j].x + b4.x + e.x;
    o.y = acc[j].y + b4.y + e.y;
    o.z = acc[j].z + b4.z + e.z;
    o.w = acc[j].w + b4.w + e.w;
    *(float4*)(A + (size_t)row * 128 + c0) = o;
  }
}

// ============================ GCN layer ============================

__global__ __launch_bounds__(256)
void gk_gcn_gemm(const float* __restrict__ X, const float* __restrict__ W,
                 const float* __restrict__ stats, const float* __restrict__ gamma,
                 const float* __restrict__ beta, float inv_n, int donorm,
                 const float* __restrict__ dinv, float* __restrict__ out) {
  __shared__ float Wl[32 * 128];
  __shared__ float Xt[32 * 68];
  __shared__ float bnscl[128];
  __shared__ float bnsh[128];
  int t = threadIdx.x;
  int row0 = blockIdx.x * 64;
  int cg = t & 31, rg = t >> 5;
  int c0 = cg * 4, r0 = rg * 8;

  if (t < 128) {
    if (donorm) {
      float mu = stats[t] * inv_n;
      float var = stats[128 + t] * inv_n - mu * mu;
      float s = gamma[t] * rsqrtf(var + BN_EPS);
      bnscl[t] = s;
      bnsh[t] = beta[t] - mu * s;
    } else {
      bnscl[t] = 1.f;
      bnsh[t] = 0.f;
    }
  }
  __syncthreads();

  float4 acc[8];
#pragma unroll
  for (int j = 0; j < 8; ++j) acc[j] = make_float4(0.f, 0.f, 0.f, 0.f);

  for (int kc = 0; kc < 128; kc += 32) {
    for (int i = t; i < 1024; i += 256) {
      ((float4*)Wl)[i] = ((const float4*)(W + (size_t)kc * 128))[i];
    }
    for (int i = t; i < 512; i += 256) {
      int r = i >> 3, q = i & 7;
      int kb = kc + q * 4;
      float4 v = *(const float4*)(X + (size_t)(row0 + r) * 128 + kb);
      if (donorm) {
        v.x = fmaf(v.x, bnscl[kb + 0], bnsh[kb + 0]);
        v.y = fmaf(v.y, bnscl[kb + 1], bnsh[kb + 1]);
        v.z = fmaf(v.z, bnscl[kb + 2], bnsh[kb + 2]);
        v.w = fmaf(v.w, bnscl[kb + 3], bnsh[kb + 3]);
        v.x = v.x > 0.f ? v.x : 0.f;
        v.y = v.y > 0.f ? v.y : 0.f;
        v.z = v.z > 0.f ? v.z : 0.f;
        v.w = v.w > 0.f ? v.w : 0.f;
      }
      Xt[(q * 4 + 0) * 68 + r] = v.x;
      Xt[(q * 4 + 1) * 68 + r] = v.y;
      Xt[(q * 4 + 2) * 68 + r] = v.z;
      Xt[(q * 4 + 3) * 68 + r] = v.w;
    }
    __syncthreads();
#pragma unroll
    for (int k = 0; k < 32; ++k) {
      float4 w = *(const float4*)&Wl[k * 128 + c0];
      float4 xa = *(const float4*)&Xt[k * 68 + r0];
      float4 xb = *(const float4*)&Xt[k * 68 + r0 + 4];
#pragma unroll
      for (int j = 0; j < 4; ++j) {
        float xv = (&xa.x)[j];
        acc[j].x = fmaf(xv, w.x, acc[j].x);
        acc[j].y = fmaf(xv, w.y, acc[j].y);
        acc[j].z = fmaf(xv, w.z, acc[j].z);
        acc[j].w = fmaf(xv, w.w, acc[j].w);
      }
#pragma unroll
      for (int j = 0; j < 4; ++j) {
        float xv = (&xb.x)[j];
        acc[4 + j].x = fmaf(xv, w.x, acc[4 + j].x);
        acc[4 + j].y = fmaf(xv, w.y, acc[4 + j].y);
        acc[4 + j].z = fmaf(xv, w.z, acc[4 + j].z);
        acc[4 + j].w = fmaf(xv, w.w, acc[4 + j].w);
      }
    }
    __syncthreads();
  }
#pragma unroll
  for (int j = 0; j < 8; ++j) {
    int row = row0 + r0 + j;
    float d = dinv[row];
    float4 o;
    o.x = acc[j].x * d;
    o.y = acc[j].y * d;
    o.z = acc[j].z * d;
    o.w = acc[j].w * d;
    *(float4*)(out + (size_t)row * 128 + c0) = o;
  }
}

// out[i] = dinv[i]*(g[i] + sum_{e in CSR[i]} g[src_e]) ; accumulates BN stats.
// 256 threads = 8 independent row-slots x 32 lanes (float4 per lane -> 1KB
// wave requests). 32 rows/block; no per-row sync. 2-edge unroll w/ index
// prefetch -> up to 4 outstanding 16B loads/thread for MLP.
__global__ __launch_bounds__(256)
void gk_agg(const float* __restrict__ g, const int* __restrict__ off,
            const int* __restrict__ csr, const float* __restrict__ dinv,
            float* __restrict__ outb, float* __restrict__ stats) {
  __shared__ float ls[128];
  __shared__ float lss[128];
  int t = threadIdx.x;
  int slot = t >> 5;
  int c0 = (t & 31) * 4;
  int i0 = blockIdx.x * 32;

  if (t < 128) { ls[t] = 0.f; lss[t] = 0.f; }
  __syncthreads();

  float4 s4 = make_float4(0.f, 0.f, 0.f, 0.f);
  float4 ss4 = make_float4(0.f, 0.f, 0.f, 0.f);

  for (int r = slot; r < 32; r += 8) {
    int i = i0 + r;
    int e0 = off[i], e1 = off[i + 1];
    float4 acc = *(const float4*)(g + (size_t)i * 128 + c0);
    int e = e0;
    int last = e1 - 1;
    int ia = 0, ib = 0;
    if (e < e1) {
      ia = csr[e];
      ib = csr[(e + 1 < e1) ? (e + 1) : last];
    }
    while (e < e1) {
      bool hb = (e + 1 < e1);
      float4 va = *(const float4*)(g + (size_t)ia * 128 + c0);
      float4 vb;
      if (hb) vb = *(const float4*)(g + (size_t)ib * 128 + c0);
      int en = e + 2;
      if (en < e1) {
        ia = csr[en];
        ib = csr[(en + 1 < e1) ? (en + 1) : last];
      }
      acc.x += va.x; acc.y += va.y; acc.z += va.z; acc.w += va.w;
      if (hb) {
        acc.x += vb.x; acc.y += vb.y; acc.z += vb.z; acc.w += vb.w;
      }
      e = en;
    }
    float d = dinv[i];
    acc.x *= d; acc.y *= d; acc.z *= d; acc.w *= d;
    *(float4*)(outb + (size_t)i * 128 + c0) = acc;
    s4.x += acc.x; s4.y += acc.y; s4.z += acc.z; s4.w += acc.w;
    ss4.x += acc.x * acc.x; ss4.y += acc.y * acc.y;
    ss4.z += acc.z * acc.z; ss4.w += acc.w * acc.w;
  }

  atomicAdd(&ls[c0 + 0], s4.x);  atomicAdd(&ls[c0 + 1], s4.y);
  atomicAdd(&ls[c0 + 2], s4.z);  atomicAdd(&ls[c0 + 3], s4.w);
  atomicAdd(&lss[c0 + 0], ss4.x); atomicAdd(&lss[c0 + 1], ss4.y);
  atomicAdd(&lss[c0 + 2], ss4.z); atomicAdd(&lss[c0 + 3], ss4.w);
  __syncthreads();
  if (t < 128) {
    atomicAdd(&stats[t], ls[t]);
    atomicAdd(&stats[t + 128], lss[t]);
  }
}

// per-graph mean of relu(bn(A)) for the last layer
__global__ __launch_bounds__(128)
void gk_pool(const float* __restrict__ A, const float* __restrict__ stats,
             const float* __restrict__ gamma, const float* __restrict__ beta,
             float inv_n, float* __restrict__ z, int npg, int zoff) {
  int gidx = blockIdx.x;
  int c = threadIdx.x;
  float mu = stats[c] * inv_n;
  float var = stats[128 + c] * inv_n - mu * mu;
  float scl = gamma[c] * rsqrtf(var + BN_EPS);
  float be = beta[c];
  float sum = 0.f;
  int r0 = gidx * npg;
  for (int r = 0; r < npg; ++r) {
    float v = (A[(size_t)(r0 + r) * 128 + c] - mu) * scl + be;
    sum += v > 0.f ? v : 0.f;
  }
  z[(size_t)gidx * 256 + zoff + c] = sum * (1.0f / (float)npg);
}

__global__ __launch_bounds__(128)
void gk_mlp(const float* __restrict__ z, const float* __restrict__ w1,
            const float* __restrict__ b1, const float* __restrict__ w2,
            const float* __restrict__ b2, float* __restrict__ out) {
  __shared__ float zs[256];
  __shared__ float red[128];
  int gidx = blockIdx.x, t = threadIdx.x;
  zs[t] = z[(size_t)gidx * 256 + t];
  zs[t + 128] = z[(size_t)gidx * 256 + 128 + t];
  __syncthreads();
  float acc = b1[t];
  for (int k = 0; k < 256; ++k) acc += zs[k] * w1[(size_t)k * 128 + t];
  acc = (acc > 0.f ? acc : 0.f) * w2[t];
  red[t] = acc;
  __syncthreads();
  for (int o = 64; o > 0; o >>= 1) {
    if (t < o) red[t] += red[t + o];
    __syncthreads();
  }
  if (t == 0) out[gidx] = red[0] + b2[0];
}

// ============================ launch ============================

extern "C" void kernel_launch(void* const* d_in, const int* in_sizes, int n_in,
                              void* d_out, int out_size, void* d_ws, size_t ws_size,
                              hipStream_t stream) {
  (void)in_sizes; (void)n_in; (void)out_size; (void)ws_size;
  const int*   lig_x       = (const int*)  d_in[0];
  const int*   rec_x_int   = (const int*)  d_in[1];
  const float* rec_x_float = (const float*)d_in[2];
  const int*   lig_ei      = (const int*)  d_in[3];
  const int*   rec_ei      = (const int*)  d_in[4];
  const int*   atom_off    = (const int*)  d_in[7];
  const float* atom_emb    = (const float*)d_in[8];
  const float* rec_emb1    = (const float*)d_in[9];
  const float* rec_w       = (const float*)d_in[10];
  const float* rec_b       = (const float*)d_in[11];
  const float* lig_W       = (const float*)d_in[12];
  const float* lig_gamma   = (const float*)d_in[14];
  const float* lig_beta    = (const float*)d_in[15];
  const float* rec_W       = (const float*)d_in[16];
  const float* rec_gamma   = (const float*)d_in[18];
  const float* rec_beta    = (const float*)d_in[19];
  const float* out_w1      = (const float*)d_in[20];
  const float* out_b1      = (const float*)d_in[21];
  const float* out_w2      = (const float*)d_in[22];
  const float* out_b2      = (const float*)d_in[23];
  float* out = (float*)d_out;

  char* p = (char*)d_ws;
  auto alloc = [&](size_t bytes) -> void* {
    void* r = p;
    p += (bytes + 255) & ~(size_t)255;
    return r;
  };
  float* A        = (float*)alloc((size_t)NREC * EMB * 4);
  float* B        = (float*)alloc((size_t)NREC * EMB * 4);
  float* dinv_lig = (float*)alloc((size_t)NLIG * 4);
  float* dinv_rec = (float*)alloc((size_t)NREC * 4);
  int*   cnt_lig  = (int*)  alloc((size_t)NLIG * 4);
  int*   cnt_rec  = (int*)  alloc((size_t)NREC * 4);
  int*   off_lig  = (int*)  alloc((size_t)(NLIG + 1) * 4);
  int*   off_rec  = (int*)  alloc((size_t)(NREC + 1) * 4);
  int*   csr_lig  = (int*)  alloc((size_t)ELIG * 4);
  int*   csr_rec  = (int*)  alloc((size_t)EREC * 4);
  int*   bsum_lig = (int*)  alloc(256 * 4);
  int*   bsum_rec = (int*)  alloc(256 * 4);
  float* stats    = (float*)alloc(256 * 4);
  float* z        = (float*)alloc((size_t)NGRAPH * 256 * 4);

  // ---- CSR build ----
  hipMemsetAsync(cnt_lig, 0, (size_t)NLIG * 4, stream);
  hipMemsetAsync(cnt_rec, 0, (size_t)NREC * 4, stream);
  gk_count<<<ELIG / 256, 256, 0, stream>>>(lig_ei + ELIG, cnt_lig, ELIG);
  gk_count<<<EREC / 256, 256, 0, stream>>>(rec_ei + EREC, cnt_rec, EREC);
  gk_scan1<<<NLIG / 1024, 256, 0, stream>>>(cnt_lig, off_lig, bsum_lig, NLIG);
  gk_scan2<<<1, 256, 0, stream>>>(bsum_lig, NLIG / 1024);
  gk_scan3<<<NLIG / 256, 256, 0, stream>>>(off_lig, bsum_lig, NLIG, ELIG);
  gk_scan1<<<NREC / 1024, 256, 0, stream>>>(cnt_rec, off_rec, bsum_rec, NREC);
  gk_scan2<<<1, 256, 0, stream>>>(bsum_rec, NREC / 1024);
  gk_scan3<<<NREC / 256, 256, 0, stream>>>(off_rec, bsum_rec, NREC, EREC);
  gk_copy<<<NLIG / 256, 256, 0, stream>>>(cnt_lig, off_lig, NLIG);
  gk_copy<<<NREC / 256, 256, 0, stream>>>(cnt_rec, off_rec, NREC);
  gk_fill<<<ELIG / 256, 256, 0, stream>>>(lig_ei, lig_ei + ELIG, cnt_lig, csr_lig, ELIG);
  gk_fill<<<EREC / 256, 256, 0, stream>>>(rec_ei, rec_ei + EREC, cnt_rec, csr_rec, EREC);
  gk_dinv<<<NLIG / 256, 256, 0, stream>>>(off_lig, dinv_lig, NLIG);
  gk_dinv<<<NREC / 256, 256, 0, stream>>>(off_rec, dinv_rec, NREC);

  auto run_entity = [&](const float* Wall, const float* gamma, const float* beta,
                        const int* offv, const int* csrv, const float* dinv,
                        int n, int npg, int zoff) {
    float inv_n = 1.0f / (float)n;
    for (int l = 0; l < 3; ++l) {
      const float* W = Wall + (size_t)l * EMB * EMB;
      const float* gm = (l > 0) ? gamma + (size_t)(l - 1) * EMB : gamma;
      const float* bt = (l > 0) ? beta + (size_t)(l - 1) * EMB : beta;
      gk_gcn_gemm<<<n / 64, 256, 0, stream>>>(A, W, stats, gm, bt, inv_n,
                                              l > 0 ? 1 : 0, dinv, B);
      hipMemsetAsync(stats, 0, 256 * 4, stream);
      gk_agg<<<n / 32, 256, 0, stream>>>(B, offv, csrv, dinv, A, stats);
    }
    gk_pool<<<NGRAPH, 128, 0, stream>>>(A, stats, gamma + 2 * EMB, beta + 2 * EMB,
                                        inv_n, z, npg, zoff);
  };

  // ---- ligand path ----
  gk_ligenc<<<NLIG, 128, 0, stream>>>(lig_x, atom_off, atom_emb, A);
  run_entity(lig_W, lig_gamma, lig_beta, off_lig, csr_lig, dinv_lig,
             NLIG, NLIG / NGRAPH, 0);

  // ---- receptor path ----
  gk_recenc<<<NREC / 64, 256, 0, stream>>>(rec_x_float, rec_x_int, rec_emb1,
                                           rec_w, rec_b, A);
  run_entity(rec_W, rec_gamma, rec_beta, off_rec, csr_rec, dinv_rec,
             NREC, NREC / NGRAPH, EMB);

  // ---- head ----
  gk_mlp<<<NGRAPH, 128, 0, stream>>>(z, out_w1, out_b1, out_w2, out_b2, out);
}

// Round 4
// 2374.231 us; speedup vs baseline: 1.5382x; 1.0728x over previous
//
#include <hip/hip_runtime.h>
#include <cstdint>
#include <cstddef>

#define EMB 128
#define NLIG 32768
#define NREC 262144
#define NGRAPH 1024
#define ELIG 327680
#define EREC 2097152
#define BN_EPS 1e-5f

// ============================ CSR build ============================

__global__ __launch_bounds__(256)
void gk_count(const int* __restrict__ dst, int* __restrict__ cnt, int E) {
  int e = blockIdx.x * 256 + threadIdx.x;
  if (e < E) atomicAdd(&cnt[dst[e]], 1);
}

__global__ __launch_bounds__(256)
void gk_scan1(const int* __restrict__ cnt, int* __restrict__ off,
              int* __restrict__ bsum, int n) {
  __shared__ int sm[256];
  int t = threadIdx.x;
  int base = blockIdx.x * 1024 + t * 4;
  int v0 = (base + 0 < n) ? cnt[base + 0] : 0;
  int v1 = (base + 1 < n) ? cnt[base + 1] : 0;
  int v2 = (base + 2 < n) ? cnt[base + 2] : 0;
  int v3 = (base + 3 < n) ? cnt[base + 3] : 0;
  int loc = v0 + v1 + v2 + v3;
  sm[t] = loc;
  __syncthreads();
  for (int o = 1; o < 256; o <<= 1) {
    int x = (t >= o) ? sm[t - o] : 0;
    __syncthreads();
    sm[t] += x;
    __syncthreads();
  }
  int run = sm[t] - loc;
  if (base + 0 < n) off[base + 0] = run;
  run += v0;
  if (base + 1 < n) off[base + 1] = run;
  run += v1;
  if (base + 2 < n) off[base + 2] = run;
  run += v2;
  if (base + 3 < n) off[base + 3] = run;
  if (t == 255) bsum[blockIdx.x] = sm[255];
}

__global__ __launch_bounds__(256)
void gk_scan2(int* __restrict__ bsum, int nb) {
  __shared__ int sm[256];
  int t = threadIdx.x;
  int v = (t < nb) ? bsum[t] : 0;
  sm[t] = v;
  __syncthreads();
  for (int o = 1; o < 256; o <<= 1) {
    int x = (t >= o) ? sm[t - o] : 0;
    __syncthreads();
    sm[t] += x;
    __syncthreads();
  }
  if (t < nb) bsum[t] = sm[t] - v;
}

__global__ __launch_bounds__(256)
void gk_scan3(int* __restrict__ off, const int* __restrict__ bsum, int n, int E) {
  int i = blockIdx.x * 256 + threadIdx.x;
  if (i < n) off[i] += bsum[i >> 10];
  if (i == 0) off[n] = E;
}

__global__ __launch_bounds__(256)
void gk_copy(int* __restrict__ d, const int* __restrict__ s, int n) {
  int i = blockIdx.x * 256 + threadIdx.x;
  if (i < n) d[i] = s[i];
}

__global__ __launch_bounds__(256)
void gk_fill(const int* __restrict__ src, const int* __restrict__ dst,
             int* __restrict__ cur, int* __restrict__ csr, int E) {
  int e = blockIdx.x * 256 + threadIdx.x;
  if (e < E) {
    int d = dst[e];
    int pos = atomicAdd(&cur[d], 1);
    csr[pos] = src[e];
  }
}

__global__ __launch_bounds__(256)
void gk_dinv(const int* __restrict__ off, float* __restrict__ dinv, int n) {
  int i = blockIdx.x * 256 + threadIdx.x;
  if (i < n) dinv[i] = rsqrtf((float)(off[i + 1] - off[i] + 1));
}

// ============================ encoders ============================

__global__ __launch_bounds__(128)
void gk_ligenc(const int* __restrict__ lig_x, const int* __restrict__ offs,
               const float* __restrict__ emb, float* __restrict__ A) {
  __shared__ int idx[9];
  int i = blockIdx.x;
  int c = threadIdx.x;
  if (c < 9) idx[c] = lig_x[i * 9 + c] + offs[c];
  __syncthreads();
  float acc = 0.f;
#pragma unroll
  for (int f = 0; f < 9; ++f) acc += emb[(size_t)idx[f] * EMB + c];
  A[(size_t)i * EMB + c] = acc;
}

// rec encoder: A = X[262144,199] @ W[199,128] + emb1[xi] + b
__global__ __launch_bounds__(256)
void gk_recenc(const float* __restrict__ X, const int* __restrict__ xi,
               const float* __restrict__ emb1, const float* __restrict__ W,
               const float* __restrict__ b, float* __restrict__ A) {
  __shared__ float Wl[32 * 128];
  __shared__ float Xt[32 * 68];
  const int K = 199;
  int t = threadIdx.x;
  int row0 = blockIdx.x * 64;
  int cg = t & 31, rg = t >> 5;
  int c0 = cg * 4, r0 = rg * 8;
  float4 acc[8];
#pragma unroll
  for (int j = 0; j < 8; ++j) acc[j] = make_float4(0.f, 0.f, 0.f, 0.f);

  for (int kc = 0; kc < K; kc += 32) {
    for (int i = t; i < 1024; i += 256) {
      int kk = i >> 5;
      float4 v = make_float4(0.f, 0.f, 0.f, 0.f);
      if (kc + kk < K) v = ((const float4*)(W + (size_t)(kc + kk) * 128))[i & 31];
      ((float4*)Wl)[i] = v;
    }
    for (int i = t; i < 512; i += 256) {
      int r = i >> 3, q = i & 7;
      int kb = kc + q * 4;
      const float* xr = X + (size_t)(row0 + r) * K;
      float v0 = (kb + 0 < K) ? xr[kb + 0] : 0.f;
      float v1 = (kb + 1 < K) ? xr[kb + 1] : 0.f;
      float v2 = (kb + 2 < K) ? xr[kb + 2] : 0.f;
      float v3 = (kb + 3 < K) ? xr[kb + 3] : 0.f;
      Xt[(q * 4 + 0) * 68 + r] = v0;
      Xt[(q * 4 + 1) * 68 + r] = v1;
      Xt[(q * 4 + 2) * 68 + r] = v2;
      Xt[(q * 4 + 3) * 68 + r] = v3;
    }
    __syncthreads();
#pragma unroll
    for (int k = 0; k < 32; ++k) {
      float4 w = *(const float4*)&Wl[k * 128 + c0];
      float4 xa = *(const float4*)&Xt[k * 68 + r0];
      float4 xb = *(const float4*)&Xt[k * 68 + r0 + 4];
#pragma unroll
      for (int j = 0; j < 4; ++j) {
        float xv = (&xa.x)[j];
        acc[j].x = fmaf(xv, w.x, acc[j].x);
        acc[j].y = fmaf(xv, w.y, acc[j].y);
        acc[j].z = fmaf(xv, w.z, acc[j].z);
        acc[j].w = fmaf(xv, w.w, acc[j].w);
      }
#pragma unroll
      for (int j = 0; j < 4; ++j) {
        float xv = (&xb.x)[j];
        acc[4 + j].x = fmaf(xv, w.x, acc[4 + j].x);
        acc[4 + j].y = fmaf(xv, w.y, acc[4 + j].y);
        acc[4 + j].z = fmaf(xv, w.z, acc[4 + j].z);
        acc[4 + j].w = fmaf(xv, w.w, acc[4 + j].w);
      }
    }
    __syncthreads();
  }
  float4 b4 = *(const float4*)(b + c0);
#pragma unroll
  for (int j = 0; j < 8; ++j) {
    int row = row0 + r0 + j;
    float4 e = *(const float4*)(emb1 + (size_t)xi[row] * 128 + c0);
    float4 o;
    o.x = acc[j].x + b4.x + e.x;
    o.y = acc[j].y + b4.y + e.y;
    o.z = acc[j].z + b4.z + e.z;
    o.w = acc[j].w + b4.w + e.w;
    *(float4*)(A + (size_t)row * 128 + c0) = o;
  }
}

// ============================ GCN layer ============================

__global__ __launch_bounds__(256)
void gk_gcn_gemm(const float* __restrict__ X, const float* __restrict__ W,
                 const float* __restrict__ stats, const float* __restrict__ gamma,
                 const float* __restrict__ beta, float inv_n, int donorm,
                 const float* __restrict__ dinv, float* __restrict__ out) {
  __shared__ float Wl[32 * 128];
  __shared__ float Xt[32 * 68];
  __shared__ float bnscl[128];
  __shared__ float bnsh[128];
  int t = threadIdx.x;
  int row0 = blockIdx.x * 64;
  int cg = t & 31, rg = t >> 5;
  int c0 = cg * 4, r0 = rg * 8;

  if (t < 128) {
    if (donorm) {
      float mu = stats[t] * inv_n;
      float var = stats[128 + t] * inv_n - mu * mu;
      float s = gamma[t] * rsqrtf(var + BN_EPS);
      bnscl[t] = s;
      bnsh[t] = beta[t] - mu * s;
    } else {
      bnscl[t] = 1.f;
      bnsh[t] = 0.f;
    }
  }
  __syncthreads();

  float4 acc[8];
#pragma unroll
  for (int j = 0; j < 8; ++j) acc[j] = make_float4(0.f, 0.f, 0.f, 0.f);

  for (int kc = 0; kc < 128; kc += 32) {
    for (int i = t; i < 1024; i += 256) {
      ((float4*)Wl)[i] = ((const float4*)(W + (size_t)kc * 128))[i];
    }
    for (int i = t; i < 512; i += 256) {
      int r = i >> 3, q = i & 7;
      int kb = kc + q * 4;
      float4 v = *(const float4*)(X + (size_t)(row0 + r) * 128 + kb);
      if (donorm) {
        v.x = fmaf(v.x, bnscl[kb + 0], bnsh[kb + 0]);
        v.y = fmaf(v.y, bnscl[kb + 1], bnsh[kb + 1]);
        v.z = fmaf(v.z, bnscl[kb + 2], bnsh[kb + 2]);
        v.w = fmaf(v.w, bnscl[kb + 3], bnsh[kb + 3]);
        v.x = v.x > 0.f ? v.x : 0.f;
        v.y = v.y > 0.f ? v.y : 0.f;
        v.z = v.z > 0.f ? v.z : 0.f;
        v.w = v.w > 0.f ? v.w : 0.f;
      }
      Xt[(q * 4 + 0) * 68 + r] = v.x;
      Xt[(q * 4 + 1) * 68 + r] = v.y;
      Xt[(q * 4 + 2) * 68 + r] = v.z;
      Xt[(q * 4 + 3) * 68 + r] = v.w;
    }
    __syncthreads();
#pragma unroll
    for (int k = 0; k < 32; ++k) {
      float4 w = *(const float4*)&Wl[k * 128 + c0];
      float4 xa = *(const float4*)&Xt[k * 68 + r0];
      float4 xb = *(const float4*)&Xt[k * 68 + r0 + 4];
#pragma unroll
      for (int j = 0; j < 4; ++j) {
        float xv = (&xa.x)[j];
        acc[j].x = fmaf(xv, w.x, acc[j].x);
        acc[j].y = fmaf(xv, w.y, acc[j].y);
        acc[j].z = fmaf(xv, w.z, acc[j].z);
        acc[j].w = fmaf(xv, w.w, acc[j].w);
      }
#pragma unroll
      for (int j = 0; j < 4; ++j) {
        float xv = (&xb.x)[j];
        acc[4 + j].x = fmaf(xv, w.x, acc[4 + j].x);
        acc[4 + j].y = fmaf(xv, w.y, acc[4 + j].y);
        acc[4 + j].z = fmaf(xv, w.z, acc[4 + j].z);
        acc[4 + j].w = fmaf(xv, w.w, acc[4 + j].w);
      }
    }
    __syncthreads();
  }
#pragma unroll
  for (int j = 0; j < 8; ++j) {
    int row = row0 + r0 + j;
    float d = dinv[row];
    float4 o;
    o.x = acc[j].x * d;
    o.y = acc[j].y * d;
    o.z = acc[j].z * d;
    o.w = acc[j].w * d;
    *(float4*)(out + (size_t)row * 128 + c0) = o;
  }
}

// out[i] = dinv[i]*(g[i] + sum_{e in CSR[i]} g[src_e]) ; accumulates BN stats.
// One row per 64-lane wave (float2/lane = 512B requests, zero intra-wave
// divergence). Edge loop: masked quads (clamped indices, 0/1 fmaf masks, no
// serial tail) with a 2-stage pipeline -> up to 8 gathers in flight/thread.
__global__ __launch_bounds__(256)
void gk_agg(const float* __restrict__ g, const int* __restrict__ off,
            const int* __restrict__ csr, const float* __restrict__ dinv,
            float* __restrict__ outb, float* __restrict__ stats) {
  __shared__ float ls[128];
  __shared__ float lss[128];
  int t = threadIdx.x;
  int slot = t >> 6;        // 4 waves per block
  int lane = t & 63;
  int c0 = lane * 2;
  int i0 = blockIdx.x * 32;

  if (t < 128) { ls[t] = 0.f; lss[t] = 0.f; }
  __syncthreads();

  float sx = 0.f, sy = 0.f, ssx = 0.f, ssy = 0.f;

  for (int r = slot; r < 32; r += 4) {
    int i = i0 + r;
    int e0 = off[i], e1 = off[i + 1];
    float2 acc = *(const float2*)(g + (size_t)i * 128 + c0);
    if (e0 < e1) {
      int last = e1 - 1;
      int e = e0;
      // quad A
      int a0 = csr[e];
      int a1 = csr[(e + 1 < e1) ? e + 1 : last];
      int a2 = csr[(e + 2 < e1) ? e + 2 : last];
      int a3 = csr[(e + 3 < e1) ? e + 3 : last];
      float2 v0 = *(const float2*)(g + (size_t)a0 * 128 + c0);
      float2 v1 = *(const float2*)(g + (size_t)a1 * 128 + c0);
      float2 v2 = *(const float2*)(g + (size_t)a2 * 128 + c0);
      float2 v3 = *(const float2*)(g + (size_t)a3 * 128 + c0);
      float m1 = (e + 1 < e1) ? 1.f : 0.f;
      float m2 = (e + 2 < e1) ? 1.f : 0.f;
      float m3 = (e + 3 < e1) ? 1.f : 0.f;
      while (e + 4 < e1) {
        int en = e + 4;
        // issue quad B before consuming quad A
        int b0 = csr[en];
        int b1 = csr[(en + 1 < e1) ? en + 1 : last];
        int b2 = csr[(en + 2 < e1) ? en + 2 : last];
        int b3 = csr[(en + 3 < e1) ? en + 3 : last];
        float2 w0 = *(const float2*)(g + (size_t)b0 * 128 + c0);
        float2 w1 = *(const float2*)(g + (size_t)b1 * 128 + c0);
        float2 w2 = *(const float2*)(g + (size_t)b2 * 128 + c0);
        float2 w3 = *(const float2*)(g + (size_t)b3 * 128 + c0);
        float n1 = (en + 1 < e1) ? 1.f : 0.f;
        float n2 = (en + 2 < e1) ? 1.f : 0.f;
        float n3 = (en + 3 < e1) ? 1.f : 0.f;
        acc.x += v0.x;
        acc.y += v0.y;
        acc.x = fmaf(v1.x, m1, acc.x); acc.y = fmaf(v1.y, m1, acc.y);
        acc.x = fmaf(v2.x, m2, acc.x); acc.y = fmaf(v2.y, m2, acc.y);
        acc.x = fmaf(v3.x, m3, acc.x); acc.y = fmaf(v3.y, m3, acc.y);
        v0 = w0; v1 = w1; v2 = w2; v3 = w3;
        m1 = n1; m2 = n2; m3 = n3;
        e = en;
      }
      acc.x += v0.x;
      acc.y += v0.y;
      acc.x = fmaf(v1.x, m1, acc.x); acc.y = fmaf(v1.y, m1, acc.y);
      acc.x = fmaf(v2.x, m2, acc.x); acc.y = fmaf(v2.y, m2, acc.y);
      acc.x = fmaf(v3.x, m3, acc.x); acc.y = fmaf(v3.y, m3, acc.y);
    }
    float d = dinv[i];
    acc.x *= d; acc.y *= d;
    *(float2*)(outb + (size_t)i * 128 + c0) = acc;
    sx += acc.x; sy += acc.y;
    ssx = fmaf(acc.x, acc.x, ssx);
    ssy = fmaf(acc.y, acc.y, ssy);
  }

  atomicAdd(&ls[c0 + 0], sx);
  atomicAdd(&ls[c0 + 1], sy);
  atomicAdd(&lss[c0 + 0], ssx);
  atomicAdd(&lss[c0 + 1], ssy);
  __syncthreads();
  if (t < 128) {
    atomicAdd(&stats[t], ls[t]);
    atomicAdd(&stats[t + 128], lss[t]);
  }
}

// per-graph mean of relu(bn(A)) for the last layer
__global__ __launch_bounds__(128)
void gk_pool(const float* __restrict__ A, const float* __restrict__ stats,
             const float* __restrict__ gamma, const float* __restrict__ beta,
             float inv_n, float* __restrict__ z, int npg, int zoff) {
  int gidx = blockIdx.x;
  int c = threadIdx.x;
  float mu = stats[c] * inv_n;
  float var = stats[128 + c] * inv_n - mu * mu;
  float scl = gamma[c] * rsqrtf(var + BN_EPS);
  float be = beta[c];
  float sum = 0.f;
  int r0 = gidx * npg;
  for (int r = 0; r < npg; ++r) {
    float v = (A[(size_t)(r0 + r) * 128 + c] - mu) * scl + be;
    sum += v > 0.f ? v : 0.f;
  }
  z[(size_t)gidx * 256 + zoff + c] = sum * (1.0f / (float)npg);
}

__global__ __launch_bounds__(128)
void gk_mlp(const float* __restrict__ z, const float* __restrict__ w1,
            const float* __restrict__ b1, const float* __restrict__ w2,
            const float* __restrict__ b2, float* __restrict__ out) {
  __shared__ float zs[256];
  __shared__ float red[128];
  int gidx = blockIdx.x, t = threadIdx.x;
  zs[t] = z[(size_t)gidx * 256 + t];
  zs[t + 128] = z[(size_t)gidx * 256 + 128 + t];
  __syncthreads();
  float acc = b1[t];
  for (int k = 0; k < 256; ++k) acc += zs[k] * w1[(size_t)k * 128 + t];
  acc = (acc > 0.f ? acc : 0.f) * w2[t];
  red[t] = acc;
  __syncthreads();
  for (int o = 64; o > 0; o >>= 1) {
    if (t < o) red[t] += red[t + o];
    __syncthreads();
  }
  if (t == 0) out[gidx] = red[0] + b2[0];
}

// ============================ launch ============================

extern "C" void kernel_launch(void* const* d_in, const int* in_sizes, int n_in,
                              void* d_out, int out_size, void* d_ws, size_t ws_size,
                              hipStream_t stream) {
  (void)in_sizes; (void)n_in; (void)out_size; (void)ws_size;
  const int*   lig_x       = (const int*)  d_in[0];
  const int*   rec_x_int   = (const int*)  d_in[1];
  const float* rec_x_float = (const float*)d_in[2];
  const int*   lig_ei      = (const int*)  d_in[3];
  const int*   rec_ei      = (const int*)  d_in[4];
  const int*   atom_off    = (const int*)  d_in[7];
  const float* atom_emb    = (const float*)d_in[8];
  const float* rec_emb1    = (const float*)d_in[9];
  const float* rec_w       = (const float*)d_in[10];
  const float* rec_b       = (const float*)d_in[11];
  const float* lig_W       = (const float*)d_in[12];
  const float* lig_gamma   = (const float*)d_in[14];
  const float* lig_beta    = (const float*)d_in[15];
  const float* rec_W       = (const float*)d_in[16];
  const float* rec_gamma   = (const float*)d_in[18];
  const float* rec_beta    = (const float*)d_in[19];
  const float* out_w1      = (const float*)d_in[20];
  const float* out_b1      = (const float*)d_in[21];
  const float* out_w2      = (const float*)d_in[22];
  const float* out_b2      = (const float*)d_in[23];
  float* out = (float*)d_out;

  char* p = (char*)d_ws;
  auto alloc = [&](size_t bytes) -> void* {
    void* r = p;
    p += (bytes + 255) & ~(size_t)255;
    return r;
  };
  float* A        = (float*)alloc((size_t)NREC * EMB * 4);
  float* B        = (float*)alloc((size_t)NREC * EMB * 4);
  float* dinv_lig = (float*)alloc((size_t)NLIG * 4);
  float* dinv_rec = (float*)alloc((size_t)NREC * 4);
  int*   cnt_lig  = (int*)  alloc((size_t)NLIG * 4);
  int*   cnt_rec  = (int*)  alloc((size_t)NREC * 4);
  int*   off_lig  = (int*)  alloc((size_t)(NLIG + 1) * 4);
  int*   off_rec  = (int*)  alloc((size_t)(NREC + 1) * 4);
  int*   csr_lig  = (int*)  alloc((size_t)ELIG * 4);
  int*   csr_rec  = (int*)  alloc((size_t)EREC * 4);
  int*   bsum_lig = (int*)  alloc(256 * 4);
  int*   bsum_rec = (int*)  alloc(256 * 4);
  float* stats    = (float*)alloc(256 * 4);
  float* z        = (float*)alloc((size_t)NGRAPH * 256 * 4);

  // ---- CSR build ----
  hipMemsetAsync(cnt_lig, 0, (size_t)NLIG * 4, stream);
  hipMemsetAsync(cnt_rec, 0, (size_t)NREC * 4, stream);
  gk_count<<<ELIG / 256, 256, 0, stream>>>(lig_ei + ELIG, cnt_lig, ELIG);
  gk_count<<<EREC / 256, 256, 0, stream>>>(rec_ei + EREC, cnt_rec, EREC);
  gk_scan1<<<NLIG / 1024, 256, 0, stream>>>(cnt_lig, off_lig, bsum_lig, NLIG);
  gk_scan2<<<1, 256, 0, stream>>>(bsum_lig, NLIG / 1024);
  gk_scan3<<<NLIG / 256, 256, 0, stream>>>(off_lig, bsum_lig, NLIG, ELIG);
  gk_scan1<<<NREC / 1024, 256, 0, stream>>>(cnt_rec, off_rec, bsum_rec, NREC);
  gk_scan2<<<1, 256, 0, stream>>>(bsum_rec, NREC / 1024);
  gk_scan3<<<NREC / 256, 256, 0, stream>>>(off_rec, bsum_rec, NREC, EREC);
  gk_copy<<<NLIG / 256, 256, 0, stream>>>(cnt_lig, off_lig, NLIG);
  gk_copy<<<NREC / 256, 256, 0, stream>>>(cnt_rec, off_rec, NREC);
  gk_fill<<<ELIG / 256, 256, 0, stream>>>(lig_ei, lig_ei + ELIG, cnt_lig, csr_lig, ELIG);
  gk_fill<<<EREC / 256, 256, 0, stream>>>(rec_ei, rec_ei + EREC, cnt_rec, csr_rec, EREC);
  gk_dinv<<<NLIG / 256, 256, 0, stream>>>(off_lig, dinv_lig, NLIG);
  gk_dinv<<<NREC / 256, 256, 0, stream>>>(off_rec, dinv_rec, NREC);

  auto run_entity = [&](const float* Wall, const float* gamma, const float* beta,
                        const int* offv, const int* csrv, const float* dinv,
                        int n, int npg, int zoff) {
    float inv_n = 1.0f / (float)n;
    for (int l = 0; l < 3; ++l) {
      const float* W = Wall + (size_t)l * EMB * EMB;
      const float* gm = (l > 0) ? gamma + (size_t)(l - 1) * EMB : gamma;
      const float* bt = (l > 0) ? beta + (size_t)(l - 1) * EMB : beta;
      gk_gcn_gemm<<<n / 64, 256, 0, stream>>>(A, W, stats, gm, bt, inv_n,
                                              l > 0 ? 1 : 0, dinv, B);
      hipMemsetAsync(stats, 0, 256 * 4, stream);
      gk_agg<<<n / 32, 256, 0, stream>>>(B, offv, csrv, dinv, A, stats);
    }
    gk_pool<<<NGRAPH, 128, 0, stream>>>(A, stats, gamma + 2 * EMB, beta + 2 * EMB,
                                        inv_n, z, npg, zoff);
  };

  // ---- ligand path ----
  gk_ligenc<<<NLIG, 128, 0, stream>>>(lig_x, atom_off, atom_emb, A);
  run_entity(lig_W, lig_gamma, lig_beta, off_lig, csr_lig, dinv_lig,
             NLIG, NLIG / NGRAPH, 0);

  // ---- receptor path ----
  gk_recenc<<<NREC / 64, 256, 0, stream>>>(rec_x_float, rec_x_int, rec_emb1,
                                           rec_w, rec_b, A);
  run_entity(rec_W, rec_gamma, rec_beta, off_rec, csr_rec, dinv_rec,
             NREC, NREC / NGRAPH, EMB);

  // ---- head ----
  gk_mlp<<<NGRAPH, 128, 0, stream>>>(z, out_w1, out_b1, out_w2, out_b2, out);
}

// Round 5
// 2283.648 us; speedup vs baseline: 1.5992x; 1.0397x over previous
//
#include <hip/hip_runtime.h>
#include <cstdint>
#include <cstddef>

#define EMB 128
#define NLIG 32768
#define NREC 262144
#define NGRAPH 1024
#define ELIG 327680
#define EREC 2097152
#define BN_EPS 1e-5f

// ============================ CSR build ============================

__global__ __launch_bounds__(256)
void gk_count(const int* __restrict__ dst, int* __restrict__ cnt, int E) {
  int e = blockIdx.x * 256 + threadIdx.x;
  if (e < E) atomicAdd(&cnt[dst[e]], 1);
}

__global__ __launch_bounds__(256)
void gk_scan1(const int* __restrict__ cnt, int* __restrict__ off,
              int* __restrict__ bsum, int n) {
  __shared__ int sm[256];
  int t = threadIdx.x;
  int base = blockIdx.x * 1024 + t * 4;
  int v0 = (base + 0 < n) ? cnt[base + 0] : 0;
  int v1 = (base + 1 < n) ? cnt[base + 1] : 0;
  int v2 = (base + 2 < n) ? cnt[base + 2] : 0;
  int v3 = (base + 3 < n) ? cnt[base + 3] : 0;
  int loc = v0 + v1 + v2 + v3;
  sm[t] = loc;
  __syncthreads();
  for (int o = 1; o < 256; o <<= 1) {
    int x = (t >= o) ? sm[t - o] : 0;
    __syncthreads();
    sm[t] += x;
    __syncthreads();
  }
  int run = sm[t] - loc;
  if (base + 0 < n) off[base + 0] = run;
  run += v0;
  if (base + 1 < n) off[base + 1] = run;
  run += v1;
  if (base + 2 < n) off[base + 2] = run;
  run += v2;
  if (base + 3 < n) off[base + 3] = run;
  if (t == 255) bsum[blockIdx.x] = sm[255];
}

__global__ __launch_bounds__(256)
void gk_scan2(int* __restrict__ bsum, int nb) {
  __shared__ int sm[256];
  int t = threadIdx.x;
  int v = (t < nb) ? bsum[t] : 0;
  sm[t] = v;
  __syncthreads();
  for (int o = 1; o < 256; o <<= 1) {
    int x = (t >= o) ? sm[t - o] : 0;
    __syncthreads();
    sm[t] += x;
    __syncthreads();
  }
  if (t < nb) bsum[t] = sm[t] - v;
}

__global__ __launch_bounds__(256)
void gk_scan3(int* __restrict__ off, const int* __restrict__ bsum, int n, int E) {
  int i = blockIdx.x * 256 + threadIdx.x;
  if (i < n) off[i] += bsum[i >> 10];
  if (i == 0) off[n] = E;
}

__global__ __launch_bounds__(256)
void gk_copy(int* __restrict__ d, const int* __restrict__ s, int n) {
  int i = blockIdx.x * 256 + threadIdx.x;
  if (i < n) d[i] = s[i];
}

__global__ __launch_bounds__(256)
void gk_fill(const int* __restrict__ src, const int* __restrict__ dst,
             int* __restrict__ cur, int* __restrict__ csr, int E) {
  int e = blockIdx.x * 256 + threadIdx.x;
  if (e < E) {
    int d = dst[e];
    int pos = atomicAdd(&cur[d], 1);
    csr[pos] = src[e];
  }
}

__global__ __launch_bounds__(256)
void gk_dinv(const int* __restrict__ off, float* __restrict__ dinv, int n) {
  int i = blockIdx.x * 256 + threadIdx.x;
  if (i < n) dinv[i] = rsqrtf((float)(off[i + 1] - off[i] + 1));
}

// ============================ encoders ============================

__global__ __launch_bounds__(128)
void gk_ligenc(const int* __restrict__ lig_x, const int* __restrict__ offs,
               const float* __restrict__ emb, float* __restrict__ A) {
  __shared__ int idx[9];
  int i = blockIdx.x;
  int c = threadIdx.x;
  if (c < 9) idx[c] = lig_x[i * 9 + c] + offs[c];
  __syncthreads();
  float acc = 0.f;
#pragma unroll
  for (int f = 0; f < 9; ++f) acc += emb[(size_t)idx[f] * EMB + c];
  A[(size_t)i * EMB + c] = acc;
}

// rec encoder: A = X[262144,199] @ W[199,128] + emb1[xi] + b
__global__ __launch_bounds__(256)
void gk_recenc(const float* __restrict__ X, const int* __restrict__ xi,
               const float* __restrict__ emb1, const float* __restrict__ W,
               const float* __restrict__ b, float* __restrict__ A) {
  __shared__ float Wl[32 * 128];
  __shared__ float Xt[32 * 68];
  const int K = 199;
  int t = threadIdx.x;
  int row0 = blockIdx.x * 64;
  int cg = t & 31, rg = t >> 5;
  int c0 = cg * 4, r0 = rg * 8;
  float4 acc[8];
#pragma unroll
  for (int j = 0; j < 8; ++j) acc[j] = make_float4(0.f, 0.f, 0.f, 0.f);

  for (int kc = 0; kc < K; kc += 32) {
    for (int i = t; i < 1024; i += 256) {
      int kk = i >> 5;
      float4 v = make_float4(0.f, 0.f, 0.f, 0.f);
      if (kc + kk < K) v = ((const float4*)(W + (size_t)(kc + kk) * 128))[i & 31];
      ((float4*)Wl)[i] = v;
    }
    for (int i = t; i < 512; i += 256) {
      int r = i >> 3, q = i & 7;
      int kb = kc + q * 4;
      const float* xr = X + (size_t)(row0 + r) * K;
      float v0 = (kb + 0 < K) ? xr[kb + 0] : 0.f;
      float v1 = (kb + 1 < K) ? xr[kb + 1] : 0.f;
      float v2 = (kb + 2 < K) ? xr[kb + 2] : 0.f;
      float v3 = (kb + 3 < K) ? xr[kb + 3] : 0.f;
      Xt[(q * 4 + 0) * 68 + r] = v0;
      Xt[(q * 4 + 1) * 68 + r] = v1;
      Xt[(q * 4 + 2) * 68 + r] = v2;
      Xt[(q * 4 + 3) * 68 + r] = v3;
    }
    __syncthreads();
#pragma unroll
    for (int k = 0; k < 32; ++k) {
      float4 w = *(const float4*)&Wl[k * 128 + c0];
      float4 xa = *(const float4*)&Xt[k * 68 + r0];
      float4 xb = *(const float4*)&Xt[k * 68 + r0 + 4];
#pragma unroll
      for (int j = 0; j < 4; ++j) {
        float xv = (&xa.x)[j];
        acc[j].x = fmaf(xv, w.x, acc[j].x);
        acc[j].y = fmaf(xv, w.y, acc[j].y);
        acc[j].z = fmaf(xv, w.z, acc[j].z);
        acc[j].w = fmaf(xv, w.w, acc[j].w);
      }
#pragma unroll
      for (int j = 0; j < 4; ++j) {
        float xv = (&xb.x)[j];
        acc[4 + j].x = fmaf(xv, w.x, acc[4 + j].x);
        acc[4 + j].y = fmaf(xv, w.y, acc[4 + j].y);
        acc[4 + j].z = fmaf(xv, w.z, acc[4 + j].z);
        acc[4 + j].w = fmaf(xv, w.w, acc[4 + j].w);
      }
    }
    __syncthreads();
  }
  float4 b4 = *(const float4*)(b + c0);
#pragma unroll
  for (int j = 0; j < 8; ++j) {
    int row = row0 + r0 + j;
    float4 e = *(const float4*)(emb1 + (size_t)xi[row] * 128 + c0);
    float4 o;
    o.x = acc[j].x + b4.x + e.x;
    o.y = acc[j].y + b4.y + e.y;
    o.z = acc[j].z + b4.z + e.z;
    o.w = acc[j].w + b4.w + e.w;
    *(float4*)(A + (size_t)row * 128 + c0) = o;
  }
}

// ============================ GCN layer ============================

__global__ __launch_bounds__(256)
void gk_gcn_gemm(const float* __restrict__ X, const float* __restrict__ W,
                 const float* __restrict__ stats, const float* __restrict__ gamma,
                 const float* __restrict__ beta, float inv_n, int donorm,
                 const float* __restrict__ dinv, float* __restrict__ out) {
  __shared__ float Wl[32 * 128];
  __shared__ float Xt[32 * 68];
  __shared__ float bnscl[128];
  __shared__ float bnsh[128];
  int t = threadIdx.x;
  int row0 = blockIdx.x * 64;
  int cg = t & 31, rg = t >> 5;
  int c0 = cg * 4, r0 = rg * 8;

  if (t < 128) {
    if (donorm) {
      float mu = stats[t] * inv_n;
      float var = stats[128 + t] * inv_n - mu * mu;
      float s = gamma[t] * rsqrtf(var + BN_EPS);
      bnscl[t] = s;
      bnsh[t] = beta[t] - mu * s;
    } else {
      bnscl[t] = 1.f;
      bnsh[t] = 0.f;
    }
  }
  __syncthreads();

  float4 acc[8];
#pragma unroll
  for (int j = 0; j < 8; ++j) acc[j] = make_float4(0.f, 0.f, 0.f, 0.f);

  for (int kc = 0; kc < 128; kc += 32) {
    for (int i = t; i < 1024; i += 256) {
      ((float4*)Wl)[i] = ((const float4*)(W + (size_t)kc * 128))[i];
    }
    for (int i = t; i < 512; i += 256) {
      int r = i >> 3, q = i & 7;
      int kb = kc + q * 4;
      float4 v = *(const float4*)(X + (size_t)(row0 + r) * 128 + kb);
      if (donorm) {
        v.x = fmaf(v.x, bnscl[kb + 0], bnsh[kb + 0]);
        v.y = fmaf(v.y, bnscl[kb + 1], bnsh[kb + 1]);
        v.z = fmaf(v.z, bnscl[kb + 2], bnsh[kb + 2]);
        v.w = fmaf(v.w, bnscl[kb + 3], bnsh[kb + 3]);
        v.x = v.x > 0.f ? v.x : 0.f;
        v.y = v.y > 0.f ? v.y : 0.f;
        v.z = v.z > 0.f ? v.z : 0.f;
        v.w = v.w > 0.f ? v.w : 0.f;
      }
      Xt[(q * 4 + 0) * 68 + r] = v.x;
      Xt[(q * 4 + 1) * 68 + r] = v.y;
      Xt[(q * 4 + 2) * 68 + r] = v.z;
      Xt[(q * 4 + 3) * 68 + r] = v.w;
    }
    __syncthreads();
#pragma unroll
    for (int k = 0; k < 32; ++k) {
      float4 w = *(const float4*)&Wl[k * 128 + c0];
      float4 xa = *(const float4*)&Xt[k * 68 + r0];
      float4 xb = *(const float4*)&Xt[k * 68 + r0 + 4];
#pragma unroll
      for (int j = 0; j < 4; ++j) {
        float xv = (&xa.x)[j];
        acc[j].x = fmaf(xv, w.x, acc[j].x);
        acc[j].y = fmaf(xv, w.y, acc[j].y);
        acc[j].z = fmaf(xv, w.z, acc[j].z);
        acc[j].w = fmaf(xv, w.w, acc[j].w);
      }
#pragma unroll
      for (int j = 0; j < 4; ++j) {
        float xv = (&xb.x)[j];
        acc[4 + j].x = fmaf(xv, w.x, acc[4 + j].x);
        acc[4 + j].y = fmaf(xv, w.y, acc[4 + j].y);
        acc[4 + j].z = fmaf(xv, w.z, acc[4 + j].z);
        acc[4 + j].w = fmaf(xv, w.w, acc[4 + j].w);
      }
    }
    __syncthreads();
  }
#pragma unroll
  for (int j = 0; j < 8; ++j) {
    int row = row0 + r0 + j;
    float d = dinv[row];
    float4 o;
    o.x = acc[j].x * d;
    o.y = acc[j].y * d;
    o.z = acc[j].z * d;
    o.w = acc[j].w * d;
    *(float4*)(out + (size_t)row * 128 + c0) = o;
  }
}

// ---------------- aggregation helpers ----------------

struct Quad {
  int i0, i1, i2, i3;
  float m0, m1, m2, m3;
};

__device__ __forceinline__ Quad load_quad(const int* __restrict__ csr,
                                          int e, int e1, int safe) {
  Quad q;
  int c0 = (e + 0 < e1) ? e + 0 : safe;
  int c1 = (e + 1 < e1) ? e + 1 : safe;
  int c2 = (e + 2 < e1) ? e + 2 : safe;
  int c3 = (e + 3 < e1) ? e + 3 : safe;
  q.i0 = csr[c0];
  q.i1 = csr[c1];
  q.i2 = csr[c2];
  q.i3 = csr[c3];
  q.m0 = (e + 0 < e1) ? 1.f : 0.f;
  q.m1 = (e + 1 < e1) ? 1.f : 0.f;
  q.m2 = (e + 2 < e1) ? 1.f : 0.f;
  q.m3 = (e + 3 < e1) ? 1.f : 0.f;
  return q;
}

__device__ __forceinline__ void gather4(const float* __restrict__ g, int c0,
                                        const Quad& q, float2* v) {
  v[0] = *(const float2*)(g + (size_t)q.i0 * 128 + c0);
  v[1] = *(const float2*)(g + (size_t)q.i1 * 128 + c0);
  v[2] = *(const float2*)(g + (size_t)q.i2 * 128 + c0);
  v[3] = *(const float2*)(g + (size_t)q.i3 * 128 + c0);
}

__device__ __forceinline__ void consume4(float2& acc, const Quad& q,
                                         const float2* v) {
  acc.x = fmaf(v[0].x, q.m0, acc.x); acc.y = fmaf(v[0].y, q.m0, acc.y);
  acc.x = fmaf(v[1].x, q.m1, acc.x); acc.y = fmaf(v[1].y, q.m1, acc.y);
  acc.x = fmaf(v[2].x, q.m2, acc.x); acc.y = fmaf(v[2].y, q.m2, acc.y);
  acc.x = fmaf(v[3].x, q.m3, acc.x); acc.y = fmaf(v[3].y, q.m3, acc.y);
}

// out[i] = dinv[i]*(g[i] + sum_{e in CSR[i]} g[src_e]) ; accumulates BN stats.
// One 64-lane wave processes TWO rows concurrently (independent cursors and
// accumulators, interleaved quad issue) -> ~2x outstanding gathers per wave.
// All edge cursors are wave-uniform -> scalar branches, no lane divergence.
// Masked quads: no serial tail; finished/empty rows run with zeroed masks.
__global__ __launch_bounds__(256)
void gk_agg(const float* __restrict__ g, const int* __restrict__ off,
            const int* __restrict__ csr, const float* __restrict__ dinv,
            float* __restrict__ outb, float* __restrict__ stats) {
  __shared__ float ls[128];
  __shared__ float lss[128];
  int t = threadIdx.x;
  int slot = t >> 6;        // 4 waves per block
  int lane = t & 63;
  int c0 = lane * 2;
  int i0 = blockIdx.x * 32;

  if (t < 128) { ls[t] = 0.f; lss[t] = 0.f; }
  __syncthreads();

  float sx = 0.f, sy = 0.f, ssx = 0.f, ssy = 0.f;

  for (int p = 0; p < 4; ++p) {
    int rA = i0 + slot * 2 + p * 8;
    int rB = rA + 1;
    int eA = off[rA], eA1 = off[rA + 1];
    int eB1 = off[rB + 1];
    int eB = eA1;  // off[rB] == off[rA+1]
    float dA = dinv[rA], dB = dinv[rB];
    float2 accA = *(const float2*)(g + (size_t)rA * 128 + c0);
    float2 accB = *(const float2*)(g + (size_t)rB * 128 + c0);
    int safeA = (eA1 > eA) ? eA1 - 1 : 0;
    int safeB = (eB1 > eB) ? eB1 - 1 : 0;

    // prologue: quad 0 for both rows
    Quad qA = load_quad(csr, eA, eA1, safeA);
    Quad qB = load_quad(csr, eB, eB1, safeB);
    float2 vA[4], vB[4];
    gather4(g, c0, qA, vA);
    gather4(g, c0, qB, vB);
    int e_A = eA + 4, e_B = eB + 4;

    while (e_A < eA1 || e_B < eB1) {
      bool an = e_A < eA1;
      bool bn = e_B < eB1;
      Quad qA2, qB2;
      float2 wA[4], wB[4];
      if (an) {
        qA2 = load_quad(csr, e_A, eA1, safeA);
        gather4(g, c0, qA2, wA);
      }
      if (bn) {
        qB2 = load_quad(csr, e_B, eB1, safeB);
        gather4(g, c0, qB2, wB);
      }
      consume4(accA, qA, vA);
      consume4(accB, qB, vB);
      if (an) {
        qA = qA2; vA[0] = wA[0]; vA[1] = wA[1]; vA[2] = wA[2]; vA[3] = wA[3];
        e_A += 4;
      } else {
        qA.m0 = qA.m1 = qA.m2 = qA.m3 = 0.f;
      }
      if (bn) {
        qB = qB2; vB[0] = wB[0]; vB[1] = wB[1]; vB[2] = wB[2]; vB[3] = wB[3];
        e_B += 4;
      } else {
        qB.m0 = qB.m1 = qB.m2 = qB.m3 = 0.f;
      }
    }
    // epilogue: consume last quads
    consume4(accA, qA, vA);
    consume4(accB, qB, vB);

    accA.x *= dA; accA.y *= dA;
    accB.x *= dB; accB.y *= dB;
    *(float2*)(outb + (size_t)rA * 128 + c0) = accA;
    *(float2*)(outb + (size_t)rB * 128 + c0) = accB;
    sx += accA.x + accB.x;
    sy += accA.y + accB.y;
    ssx = fmaf(accA.x, accA.x, ssx); ssx = fmaf(accB.x, accB.x, ssx);
    ssy = fmaf(accA.y, accA.y, ssy); ssy = fmaf(accB.y, accB.y, ssy);
  }

  atomicAdd(&ls[c0 + 0], sx);
  atomicAdd(&ls[c0 + 1], sy);
  atomicAdd(&lss[c0 + 0], ssx);
  atomicAdd(&lss[c0 + 1], ssy);
  __syncthreads();
  if (t < 128) {
    atomicAdd(&stats[t], ls[t]);
    atomicAdd(&stats[t + 128], lss[t]);
  }
}

// per-graph mean of relu(bn(A)) for the last layer
__global__ __launch_bounds__(128)
void gk_pool(const float* __restrict__ A, const float* __restrict__ stats,
             const float* __restrict__ gamma, const float* __restrict__ beta,
             float inv_n, float* __restrict__ z, int npg, int zoff) {
  int gidx = blockIdx.x;
  int c = threadIdx.x;
  float mu = stats[c] * inv_n;
  float var = stats[128 + c] * inv_n - mu * mu;
  float scl = gamma[c] * rsqrtf(var + BN_EPS);
  float be = beta[c];
  float sum = 0.f;
  int r0 = gidx * npg;
  for (int r = 0; r < npg; ++r) {
    float v = (A[(size_t)(r0 + r) * 128 + c] - mu) * scl + be;
    sum += v > 0.f ? v : 0.f;
  }
  z[(size_t)gidx * 256 + zoff + c] = sum * (1.0f / (float)npg);
}

__global__ __launch_bounds__(128)
void gk_mlp(const float* __restrict__ z, const float* __restrict__ w1,
            const float* __restrict__ b1, const float* __restrict__ w2,
            const float* __restrict__ b2, float* __restrict__ out) {
  __shared__ float zs[256];
  __shared__ float red[128];
  int gidx = blockIdx.x, t = threadIdx.x;
  zs[t] = z[(size_t)gidx * 256 + t];
  zs[t + 128] = z[(size_t)gidx * 256 + 128 + t];
  __syncthreads();
  float acc = b1[t];
  for (int k = 0; k < 256; ++k) acc += zs[k] * w1[(size_t)k * 128 + t];
  acc = (acc > 0.f ? acc : 0.f) * w2[t];
  red[t] = acc;
  __syncthreads();
  for (int o = 64; o > 0; o >>= 1) {
    if (t < o) red[t] += red[t + o];
    __syncthreads();
  }
  if (t == 0) out[gidx] = red[0] + b2[0];
}

// ============================ launch ============================

extern "C" void kernel_launch(void* const* d_in, const int* in_sizes, int n_in,
                              void* d_out, int out_size, void* d_ws, size_t ws_size,
                              hipStream_t stream) {
  (void)in_sizes; (void)n_in; (void)out_size; (void)ws_size;
  const int*   lig_x       = (const int*)  d_in[0];
  const int*   rec_x_int   = (const int*)  d_in[1];
  const float* rec_x_float = (const float*)d_in[2];
  const int*   lig_ei      = (const int*)  d_in[3];
  const int*   rec_ei      = (const int*)  d_in[4];
  const int*   atom_off    = (const int*)  d_in[7];
  const float* atom_emb    = (const float*)d_in[8];
  const float* rec_emb1    = (const float*)d_in[9];
  const float* rec_w       = (const float*)d_in[10];
  const float* rec_b       = (const float*)d_in[11];
  const float* lig_W       = (const float*)d_in[12];
  const float* lig_gamma   = (const float*)d_in[14];
  const float* lig_beta    = (const float*)d_in[15];
  const float* rec_W       = (const float*)d_in[16];
  const float* rec_gamma   = (const float*)d_in[18];
  const float* rec_beta    = (const float*)d_in[19];
  const float* out_w1      = (const float*)d_in[20];
  const float* out_b1      = (const float*)d_in[21];
  const float* out_w2      = (const float*)d_in[22];
  const float* out_b2      = (const float*)d_in[23];
  float* out = (float*)d_out;

  char* p = (char*)d_ws;
  auto alloc = [&](size_t bytes) -> void* {
    void* r = p;
    p += (bytes + 255) & ~(size_t)255;
    return r;
  };
  float* A        = (float*)alloc((size_t)NREC * EMB * 4);
  float* B        = (float*)alloc((size_t)NREC * EMB * 4);
  float* dinv_lig = (float*)alloc((size_t)NLIG * 4);
  float* dinv_rec = (float*)alloc((size_t)NREC * 4);
  int*   cnt_lig  = (int*)  alloc((size_t)NLIG * 4);
  int*   cnt_rec  = (int*)  alloc((size_t)NREC * 4);
  int*   off_lig  = (int*)  alloc((size_t)(NLIG + 1) * 4);
  int*   off_rec  = (int*)  alloc((size_t)(NREC + 1) * 4);
  int*   csr_lig  = (int*)  alloc((size_t)ELIG * 4);
  int*   csr_rec  = (int*)  alloc((size_t)EREC * 4);
  int*   bsum_lig = (int*)  alloc(256 * 4);
  int*   bsum_rec = (int*)  alloc(256 * 4);
  float* stats    = (float*)alloc(256 * 4);
  float* z        = (float*)alloc((size_t)NGRAPH * 256 * 4);

  // ---- CSR build ----
  hipMemsetAsync(cnt_lig, 0, (size_t)NLIG * 4, stream);
  hipMemsetAsync(cnt_rec, 0, (size_t)NREC * 4, stream);
  gk_count<<<ELIG / 256, 256, 0, stream>>>(lig_ei + ELIG, cnt_lig, ELIG);
  gk_count<<<EREC / 256, 256, 0, stream>>>(rec_ei + EREC, cnt_rec, EREC);
  gk_scan1<<<NLIG / 1024, 256, 0, stream>>>(cnt_lig, off_lig, bsum_lig, NLIG);
  gk_scan2<<<1, 256, 0, stream>>>(bsum_lig, NLIG / 1024);
  gk_scan3<<<NLIG / 256, 256, 0, stream>>>(off_lig, bsum_lig, NLIG, ELIG);
  gk_scan1<<<NREC / 1024, 256, 0, stream>>>(cnt_rec, off_rec, bsum_rec, NREC);
  gk_scan2<<<1, 256, 0, stream>>>(bsum_rec, NREC / 1024);
  gk_scan3<<<NREC / 256, 256, 0, stream>>>(off_rec, bsum_rec, NREC, EREC);
  gk_copy<<<NLIG / 256, 256, 0, stream>>>(cnt_lig, off_lig, NLIG);
  gk_copy<<<NREC / 256, 256, 0, stream>>>(cnt_rec, off_rec, NREC);
  gk_fill<<<ELIG / 256, 256, 0, stream>>>(lig_ei, lig_ei + ELIG, cnt_lig, csr_lig, ELIG);
  gk_fill<<<EREC / 256, 256, 0, stream>>>(rec_ei, rec_ei + EREC, cnt_rec, csr_rec, EREC);
  gk_dinv<<<NLIG / 256, 256, 0, stream>>>(off_lig, dinv_lig, NLIG);
  gk_dinv<<<NREC / 256, 256, 0, stream>>>(off_rec, dinv_rec, NREC);

  auto run_entity = [&](const float* Wall, const float* gamma, const float* beta,
                        const int* offv, const int* csrv, const float* dinv,
                        int n, int npg, int zoff) {
    float inv_n = 1.0f / (float)n;
    for (int l = 0; l < 3; ++l) {
      const float* W = Wall + (size_t)l * EMB * EMB;
      const float* gm = (l > 0) ? gamma + (size_t)(l - 1) * EMB : gamma;
      const float* bt = (l > 0) ? beta + (size_t)(l - 1) * EMB : beta;
      gk_gcn_gemm<<<n / 64, 256, 0, stream>>>(A, W, stats, gm, bt, inv_n,
                                              l > 0 ? 1 : 0, dinv, B);
      hipMemsetAsync(stats, 0, 256 * 4, stream);
      gk_agg<<<n / 32, 256, 0, stream>>>(B, offv, csrv, dinv, A, stats);
    }
    gk_pool<<<NGRAPH, 128, 0, stream>>>(A, stats, gamma + 2 * EMB, beta + 2 * EMB,
                                        inv_n, z, npg, zoff);
  };

  // ---- ligand path ----
  gk_ligenc<<<NLIG, 128, 0, stream>>>(lig_x, atom_off, atom_emb, A);
  run_entity(lig_W, lig_gamma, lig_beta, off_lig, csr_lig, dinv_lig,
             NLIG, NLIG / NGRAPH, 0);

  // ---- receptor path ----
  gk_recenc<<<NREC / 64, 256, 0, stream>>>(rec_x_float, rec_x_int, rec_emb1,
                                           rec_w, rec_b, A);
  run_entity(rec_W, rec_gamma, rec_beta, off_rec, csr_rec, dinv_rec,
             NREC, NREC / NGRAPH, EMB);

  // ---- head ----
  gk_mlp<<<NGRAPH, 128, 0, stream>>>(z, out_w1, out_b1, out_w2, out_b2, out);
}

// Round 6
// 1857.213 us; speedup vs baseline: 1.9664x; 1.2296x over previous
//
#include <hip/hip_runtime.h>
#include <hip/hip_bf16.h>
#include <cstdint>
#include <cstddef>

#define EMB 128
#define NLIG 32768
#define NREC 262144
#define NGRAPH 1024
#define ELIG 327680
#define EREC 2097152
#define BN_EPS 1e-5f

typedef unsigned short ushort_t;
typedef short bf16x8 __attribute__((ext_vector_type(8)));
typedef float f32x4 __attribute__((ext_vector_type(4)));

__device__ __forceinline__ float bf2f(ushort_t u) {
  union { unsigned int i; float f; } v;
  v.i = ((unsigned int)u) << 16;
  return v.f;
}
__device__ __forceinline__ ushort_t f2bf(float f) {
  __hip_bfloat16 h = __float2bfloat16(f);  // RNE
  union { __hip_bfloat16 h; ushort_t u; } v;
  v.h = h;
  return v.u;
}

// ============================ CSR build ============================

__global__ __launch_bounds__(256)
void gk_count(const int* __restrict__ dst, int* __restrict__ cnt, int E) {
  int e = blockIdx.x * 256 + threadIdx.x;
  if (e < E) atomicAdd(&cnt[dst[e]], 1);
}

__global__ __launch_bounds__(256)
void gk_scan1(const int* __restrict__ cnt, int* __restrict__ off,
              int* __restrict__ bsum, int n) {
  __shared__ int sm[256];
  int t = threadIdx.x;
  int base = blockIdx.x * 1024 + t * 4;
  int v0 = (base + 0 < n) ? cnt[base + 0] : 0;
  int v1 = (base + 1 < n) ? cnt[base + 1] : 0;
  int v2 = (base + 2 < n) ? cnt[base + 2] : 0;
  int v3 = (base + 3 < n) ? cnt[base + 3] : 0;
  int loc = v0 + v1 + v2 + v3;
  sm[t] = loc;
  __syncthreads();
  for (int o = 1; o < 256; o <<= 1) {
    int x = (t >= o) ? sm[t - o] : 0;
    __syncthreads();
    sm[t] += x;
    __syncthreads();
  }
  int run = sm[t] - loc;
  if (base + 0 < n) off[base + 0] = run;
  run += v0;
  if (base + 1 < n) off[base + 1] = run;
  run += v1;
  if (base + 2 < n) off[base + 2] = run;
  run += v2;
  if (base + 3 < n) off[base + 3] = run;
  if (t == 255) bsum[blockIdx.x] = sm[255];
}

__global__ __launch_bounds__(256)
void gk_scan2(int* __restrict__ bsum, int nb) {
  __shared__ int sm[256];
  int t = threadIdx.x;
  int v = (t < nb) ? bsum[t] : 0;
  sm[t] = v;
  __syncthreads();
  for (int o = 1; o < 256; o <<= 1) {
    int x = (t >= o) ? sm[t - o] : 0;
    __syncthreads();
    sm[t] += x;
    __syncthreads();
  }
  if (t < nb) bsum[t] = sm[t] - v;
}

__global__ __launch_bounds__(256)
void gk_scan3(int* __restrict__ off, const int* __restrict__ bsum, int n, int E) {
  int i = blockIdx.x * 256 + threadIdx.x;
  if (i < n) off[i] += bsum[i >> 10];
  if (i == 0) off[n] = E;
}

__global__ __launch_bounds__(256)
void gk_copy(int* __restrict__ d, const int* __restrict__ s, int n) {
  int i = blockIdx.x * 256 + threadIdx.x;
  if (i < n) d[i] = s[i];
}

__global__ __launch_bounds__(256)
void gk_fill(const int* __restrict__ src, const int* __restrict__ dst,
             int* __restrict__ cur, int* __restrict__ csr, int E) {
  int e = blockIdx.x * 256 + threadIdx.x;
  if (e < E) {
    int d = dst[e];
    int pos = atomicAdd(&cur[d], 1);
    csr[pos] = src[e];
  }
}

__global__ __launch_bounds__(256)
void gk_dinv(const int* __restrict__ off, float* __restrict__ dinv, int n) {
  int i = blockIdx.x * 256 + threadIdx.x;
  if (i < n) dinv[i] = rsqrtf((float)(off[i + 1] - off[i] + 1));
}

// ============================ encoders ============================

__global__ __launch_bounds__(128)
void gk_ligenc(const int* __restrict__ lig_x, const int* __restrict__ offs,
               const float* __restrict__ emb, ushort_t* __restrict__ A) {
  __shared__ int idx[9];
  int i = blockIdx.x;
  int c = threadIdx.x;
  if (c < 9) idx[c] = lig_x[i * 9 + c] + offs[c];
  __syncthreads();
  float acc = 0.f;
#pragma unroll
  for (int f = 0; f < 9; ++f) acc += emb[(size_t)idx[f] * EMB + c];
  A[(size_t)i * EMB + c] = f2bf(acc);
}

// rec encoder: A = X[262144,199] @ W[199,128] + emb1[xi] + b   (fp32 compute,
// bf16 output)
__global__ __launch_bounds__(256)
void gk_recenc(const float* __restrict__ X, const int* __restrict__ xi,
               const float* __restrict__ emb1, const float* __restrict__ W,
               const float* __restrict__ b, ushort_t* __restrict__ A) {
  __shared__ float Wl[32 * 128];
  __shared__ float Xt[32 * 68];
  const int K = 199;
  int t = threadIdx.x;
  int row0 = blockIdx.x * 64;
  int cg = t & 31, rg = t >> 5;
  int c0 = cg * 4, r0 = rg * 8;
  float4 acc[8];
#pragma unroll
  for (int j = 0; j < 8; ++j) acc[j] = make_float4(0.f, 0.f, 0.f, 0.f);

  for (int kc = 0; kc < K; kc += 32) {
    for (int i = t; i < 1024; i += 256) {
      int kk = i >> 5;
      float4 v = make_float4(0.f, 0.f, 0.f, 0.f);
      if (kc + kk < K) v = ((const float4*)(W + (size_t)(kc + kk) * 128))[i & 31];
      ((float4*)Wl)[i] = v;
    }
    for (int i = t; i < 512; i += 256) {
      int r = i >> 3, q = i & 7;
      int kb = kc + q * 4;
      const float* xr = X + (size_t)(row0 + r) * K;
      float v0 = (kb + 0 < K) ? xr[kb + 0] : 0.f;
      float v1 = (kb + 1 < K) ? xr[kb + 1] : 0.f;
      float v2 = (kb + 2 < K) ? xr[kb + 2] : 0.f;
      float v3 = (kb + 3 < K) ? xr[kb + 3] : 0.f;
      Xt[(q * 4 + 0) * 68 + r] = v0;
      Xt[(q * 4 + 1) * 68 + r] = v1;
      Xt[(q * 4 + 2) * 68 + r] = v2;
      Xt[(q * 4 + 3) * 68 + r] = v3;
    }
    __syncthreads();
#pragma unroll
    for (int k = 0; k < 32; ++k) {
      float4 w = *(const float4*)&Wl[k * 128 + c0];
      float4 xa = *(const float4*)&Xt[k * 68 + r0];
      float4 xb = *(const float4*)&Xt[k * 68 + r0 + 4];
#pragma unroll
      for (int j = 0; j < 4; ++j) {
        float xv = (&xa.x)[j];
        acc[j].x = fmaf(xv, w.x, acc[j].x);
        acc[j].y = fmaf(xv, w.y, acc[j].y);
        acc[j].z = fmaf(xv, w.z, acc[j].z);
        acc[j].w = fmaf(xv, w.w, acc[j].w);
      }
#pragma unroll
      for (int j = 0; j < 4; ++j) {
        float xv = (&xb.x)[j];
        acc[4 + j].x = fmaf(xv, w.x, acc[4 + j].x);
        acc[4 + j].y = fmaf(xv, w.y, acc[4 + j].y);
        acc[4 + j].z = fmaf(xv, w.z, acc[4 + j].z);
        acc[4 + j].w = fmaf(xv, w.w, acc[4 + j].w);
      }
    }
    __syncthreads();
  }
  float4 b4 = *(const float4*)(b + c0);
#pragma unroll
  for (int j = 0; j < 8; ++j) {
    int row = row0 + r0 + j;
    float4 e = *(const float4*)(emb1 + (size_t)xi[row] * 128 + c0);
    uint2 o;
    o.x = (unsigned int)f2bf(acc[j].x + b4.x + e.x) |
          ((unsigned int)f2bf(acc[j].y + b4.y + e.y) << 16);
    o.y = (unsigned int)f2bf(acc[j].z + b4.z + e.z) |
          ((unsigned int)f2bf(acc[j].w + b4.w + e.w) << 16);
    *(uint2*)(A + (size_t)row * 128 + c0) = o;
  }
}

// ======================= per-layer prep =======================
// Computes BN scale/shift from stats, and W^T in bf16.
__global__ __launch_bounds__(256)
void gk_prep(const float* __restrict__ W, const float* __restrict__ stats,
             const float* __restrict__ gamma, const float* __restrict__ beta,
             float inv_n, int donorm, ushort_t* __restrict__ Wt,
             float* __restrict__ bnscl, float* __restrict__ bnsh) {
  int idx = blockIdx.x * 256 + threadIdx.x;
  if (idx < 128) {
    if (donorm) {
      float mu = stats[idx] * inv_n;
      float var = stats[128 + idx] * inv_n - mu * mu;
      float s = gamma[idx] * rsqrtf(var + BN_EPS);
      bnscl[idx] = s;
      bnsh[idx] = beta[idx] - mu * s;
    } else {
      bnscl[idx] = 1.f;
      bnsh[idx] = 0.f;
    }
  }
  int c = idx >> 7, k = idx & 127;
  Wt[(size_t)c * 128 + k] = f2bf(W[(size_t)k * 128 + c]);
}

// ====================== MFMA GCN GEMM ======================
// g_bf = (relu(bn(X_bf)) @ W) * dinv[row], bf16 in/out, MFMA 16x16x32.
// 128x128 tile per block (4 waves). X and W^T staged to LDS bf16 with
// XOR-swizzled 16B chunks (conflict-free, no padding -> exactly 64KB LDS).
// Verified layouts: A[m=lane&15][k=quad*8+j]; B[k=quad*8+j][n=lane&15];
// C/D col=lane&15, row=quad*4+reg.
__global__ __launch_bounds__(256)
void gk_mm(const ushort_t* __restrict__ Xb, const ushort_t* __restrict__ Wt,
           const float* __restrict__ bnscl, const float* __restrict__ bnsh,
           int donorm, const float* __restrict__ dinv,
           ushort_t* __restrict__ gb) {
  __shared__ ushort_t Xs[128 * 128];
  __shared__ ushort_t Ws[128 * 128];
  int t = threadIdx.x;
  int row0 = blockIdx.x * 128;

  // stage X with BN+ReLU (chunk = 8 bf16 = 16B; swizzle chunk ^= (row&15))
  for (int i = t; i < 2048; i += 256) {
    int r = i >> 4, cc = i & 15;
    union { uint4 v; ushort_t s[8]; } u;
    u.v = *(const uint4*)(Xb + (size_t)(row0 + r) * 128 + cc * 8);
    if (donorm) {
#pragma unroll
      for (int j = 0; j < 8; ++j) {
        int k = cc * 8 + j;
        float f = fmaf(bf2f(u.s[j]), bnscl[k], bnsh[k]);
        f = f > 0.f ? f : 0.f;
        u.s[j] = f2bf(f);
      }
    }
    *(uint4*)&Xs[r * 128 + ((cc ^ (r & 15)) * 8)] = u.v;
  }
  // stage W^T (already bf16; swizzle chunk ^= (c&15))
  for (int i = t; i < 2048; i += 256) {
    int c = i >> 4, cc = i & 15;
    uint4 u = *(const uint4*)(Wt + (size_t)c * 128 + cc * 8);
    *(uint4*)&Ws[c * 128 + ((cc ^ (c & 15)) * 8)] = u;
  }
  __syncthreads();

  int w = t >> 6, lane = t & 63;
  int m = lane & 15, quad = lane >> 4;
  int rbase = w * 32;

  f32x4 acc[2][8];
#pragma unroll
  for (int rt = 0; rt < 2; ++rt)
#pragma unroll
    for (int ct = 0; ct < 8; ++ct) acc[rt][ct] = (f32x4){0.f, 0.f, 0.f, 0.f};

#pragma unroll
  for (int kc8 = 0; kc8 < 16; kc8 += 4) {  // K-chunks of 32 (4 chunks of 8)
    int ck = (kc8 + quad) ^ m;             // swizzled chunk index
    bf16x8 a0 = *(const bf16x8*)&Xs[(rbase + m) * 128 + ck * 8];
    bf16x8 a1 = *(const bf16x8*)&Xs[(rbase + 16 + m) * 128 + ck * 8];
#pragma unroll
    for (int ct = 0; ct < 8; ++ct) {
      bf16x8 b = *(const bf16x8*)&Ws[(ct * 16 + m) * 128 + ck * 8];
      acc[0][ct] = __builtin_amdgcn_mfma_f32_16x16x32_bf16(a0, b, acc[0][ct], 0, 0, 0);
      acc[1][ct] = __builtin_amdgcn_mfma_f32_16x16x32_bf16(a1, b, acc[1][ct], 0, 0, 0);
    }
  }

#pragma unroll
  for (int rt = 0; rt < 2; ++rt) {
    int rb = row0 + rbase + rt * 16 + quad * 4;
    float d0 = dinv[rb + 0], d1 = dinv[rb + 1];
    float d2 = dinv[rb + 2], d3 = dinv[rb + 3];
#pragma unroll
    for (int ct = 0; ct < 8; ++ct) {
      int c = ct * 16 + m;
      gb[(size_t)(rb + 0) * 128 + c] = f2bf(acc[rt][ct][0] * d0);
      gb[(size_t)(rb + 1) * 128 + c] = f2bf(acc[rt][ct][1] * d1);
      gb[(size_t)(rb + 2) * 128 + c] = f2bf(acc[rt][ct][2] * d2);
      gb[(size_t)(rb + 3) * 128 + c] = f2bf(acc[rt][ct][3] * d3);
    }
  }
}

// ---------------- aggregation helpers ----------------

struct Quad {
  int i0, i1, i2, i3;
  float m0, m1, m2, m3;
};

__device__ __forceinline__ Quad load_quad(const int* __restrict__ csr,
                                          int e, int e1, int safe) {
  Quad q;
  int c0 = (e + 0 < e1) ? e + 0 : safe;
  int c1 = (e + 1 < e1) ? e + 1 : safe;
  int c2 = (e + 2 < e1) ? e + 2 : safe;
  int c3 = (e + 3 < e1) ? e + 3 : safe;
  q.i0 = csr[c0];
  q.i1 = csr[c1];
  q.i2 = csr[c2];
  q.i3 = csr[c3];
  q.m0 = (e + 0 < e1) ? 1.f : 0.f;
  q.m1 = (e + 1 < e1) ? 1.f : 0.f;
  q.m2 = (e + 2 < e1) ? 1.f : 0.f;
  q.m3 = (e + 3 < e1) ? 1.f : 0.f;
  return q;
}

__device__ __forceinline__ void gather4(const ushort_t* __restrict__ g, int c0,
                                        const Quad& q, unsigned int* v) {
  v[0] = *(const unsigned int*)(g + (size_t)q.i0 * 128 + c0);
  v[1] = *(const unsigned int*)(g + (size_t)q.i1 * 128 + c0);
  v[2] = *(const unsigned int*)(g + (size_t)q.i2 * 128 + c0);
  v[3] = *(const unsigned int*)(g + (size_t)q.i3 * 128 + c0);
}

__device__ __forceinline__ void consume4(float2& acc, const Quad& q,
                                         const unsigned int* v) {
  float lo0 = bf2f((ushort_t)(v[0] & 0xffffu)), hi0 = bf2f((ushort_t)(v[0] >> 16));
  float lo1 = bf2f((ushort_t)(v[1] & 0xffffu)), hi1 = bf2f((ushort_t)(v[1] >> 16));
  float lo2 = bf2f((ushort_t)(v[2] & 0xffffu)), hi2 = bf2f((ushort_t)(v[2] >> 16));
  float lo3 = bf2f((ushort_t)(v[3] & 0xffffu)), hi3 = bf2f((ushort_t)(v[3] >> 16));
  acc.x = fmaf(lo0, q.m0, acc.x); acc.y = fmaf(hi0, q.m0, acc.y);
  acc.x = fmaf(lo1, q.m1, acc.x); acc.y = fmaf(hi1, q.m1, acc.y);
  acc.x = fmaf(lo2, q.m2, acc.x); acc.y = fmaf(hi2, q.m2, acc.y);
  acc.x = fmaf(lo3, q.m3, acc.x); acc.y = fmaf(hi3, q.m3, acc.y);
}

// out[i] = dinv[i]*(g[i] + sum_{e in CSR[i]} g[src_e]) ; bf16 in/out, fp32
// accumulate + BN stats. One 64-lane wave handles TWO rows concurrently.
__global__ __launch_bounds__(256)
void gk_agg(const ushort_t* __restrict__ g, const int* __restrict__ off,
            const int* __restrict__ csr, const float* __restrict__ dinv,
            ushort_t* __restrict__ outb, float* __restrict__ stats) {
  __shared__ float ls[128];
  __shared__ float lss[128];
  int t = threadIdx.x;
  int slot = t >> 6;        // 4 waves per block
  int lane = t & 63;
  int c0 = lane * 2;
  int i0 = blockIdx.x * 32;

  if (t < 128) { ls[t] = 0.f; lss[t] = 0.f; }
  __syncthreads();

  float sx = 0.f, sy = 0.f, ssx = 0.f, ssy = 0.f;

  for (int p = 0; p < 4; ++p) {
    int rA = i0 + slot * 2 + p * 8;
    int rB = rA + 1;
    int eA = off[rA], eA1 = off[rA + 1];
    int eB1 = off[rB + 1];
    int eB = eA1;
    float dA = dinv[rA], dB = dinv[rB];
    unsigned int uA = *(const unsigned int*)(g + (size_t)rA * 128 + c0);
    unsigned int uB = *(const unsigned int*)(g + (size_t)rB * 128 + c0);
    float2 accA = make_float2(bf2f((ushort_t)(uA & 0xffffu)),
                              bf2f((ushort_t)(uA >> 16)));
    float2 accB = make_float2(bf2f((ushort_t)(uB & 0xffffu)),
                              bf2f((ushort_t)(uB >> 16)));
    int safeA = (eA1 > eA) ? eA1 - 1 : 0;
    int safeB = (eB1 > eB) ? eB1 - 1 : 0;

    Quad qA = load_quad(csr, eA, eA1, safeA);
    Quad qB = load_quad(csr, eB, eB1, safeB);
    unsigned int vA[4], vB[4];
    gather4(g, c0, qA, vA);
    gather4(g, c0, qB, vB);
    int e_A = eA + 4, e_B = eB + 4;

    while (e_A < eA1 || e_B < eB1) {
      bool an = e_A < eA1;
      bool bn = e_B < eB1;
      Quad qA2, qB2;
      unsigned int wA[4], wB[4];
      if (an) {
        qA2 = load_quad(csr, e_A, eA1, safeA);
        gather4(g, c0, qA2, wA);
      }
      if (bn) {
        qB2 = load_quad(csr, e_B, eB1, safeB);
        gather4(g, c0, qB2, wB);
      }
      consume4(accA, qA, vA);
      consume4(accB, qB, vB);
      if (an) {
        qA = qA2; vA[0] = wA[0]; vA[1] = wA[1]; vA[2] = wA[2]; vA[3] = wA[3];
        e_A += 4;
      } else {
        qA.m0 = qA.m1 = qA.m2 = qA.m3 = 0.f;
      }
      if (bn) {
        qB = qB2; vB[0] = wB[0]; vB[1] = wB[1]; vB[2] = wB[2]; vB[3] = wB[3];
        e_B += 4;
      } else {
        qB.m0 = qB.m1 = qB.m2 = qB.m3 = 0.f;
      }
    }
    consume4(accA, qA, vA);
    consume4(accB, qB, vB);

    accA.x *= dA; accA.y *= dA;
    accB.x *= dB; accB.y *= dB;
    unsigned int oA = (unsigned int)f2bf(accA.x) | ((unsigned int)f2bf(accA.y) << 16);
    unsigned int oB = (unsigned int)f2bf(accB.x) | ((unsigned int)f2bf(accB.y) << 16);
    *(unsigned int*)(outb + (size_t)rA * 128 + c0) = oA;
    *(unsigned int*)(outb + (size_t)rB * 128 + c0) = oB;
    sx += accA.x + accB.x;
    sy += accA.y + accB.y;
    ssx = fmaf(accA.x, accA.x, ssx); ssx = fmaf(accB.x, accB.x, ssx);
    ssy = fmaf(accA.y, accA.y, ssy); ssy = fmaf(accB.y, accB.y, ssy);
  }

  atomicAdd(&ls[c0 + 0], sx);
  atomicAdd(&ls[c0 + 1], sy);
  atomicAdd(&lss[c0 + 0], ssx);
  atomicAdd(&lss[c0 + 1], ssy);
  __syncthreads();
  if (t < 128) {
    atomicAdd(&stats[t], ls[t]);
    atomicAdd(&stats[t + 128], lss[t]);
  }
}

// per-graph mean of relu(bn(A_bf)) for the last layer
__global__ __launch_bounds__(128)
void gk_pool(const ushort_t* __restrict__ A, const float* __restrict__ stats,
             const float* __restrict__ gamma, const float* __restrict__ beta,
             float inv_n, float* __restrict__ z, int npg, int zoff) {
  int gidx = blockIdx.x;
  int c = threadIdx.x;
  float mu = stats[c] * inv_n;
  float var = stats[128 + c] * inv_n - mu * mu;
  float scl = gamma[c] * rsqrtf(var + BN_EPS);
  float be = beta[c];
  float sum = 0.f;
  int r0 = gidx * npg;
  for (int r = 0; r < npg; ++r) {
    float v = (bf2f(A[(size_t)(r0 + r) * 128 + c]) - mu) * scl + be;
    sum += v > 0.f ? v : 0.f;
  }
  z[(size_t)gidx * 256 + zoff + c] = sum * (1.0f / (float)npg);
}

__global__ __launch_bounds__(128)
void gk_mlp(const float* __restrict__ z, const float* __restrict__ w1,
            const float* __restrict__ b1, const float* __restrict__ w2,
            const float* __restrict__ b2, float* __restrict__ out) {
  __shared__ float zs[256];
  __shared__ float red[128];
  int gidx = blockIdx.x, t = threadIdx.x;
  zs[t] = z[(size_t)gidx * 256 + t];
  zs[t + 128] = z[(size_t)gidx * 256 + 128 + t];
  __syncthreads();
  float acc = b1[t];
  for (int k = 0; k < 256; ++k) acc += zs[k] * w1[(size_t)k * 128 + t];
  acc = (acc > 0.f ? acc : 0.f) * w2[t];
  red[t] = acc;
  __syncthreads();
  for (int o = 64; o > 0; o >>= 1) {
    if (t < o) red[t] += red[t + o];
    __syncthreads();
  }
  if (t == 0) out[gidx] = red[0] + b2[0];
}

// ============================ launch ============================

extern "C" void kernel_launch(void* const* d_in, const int* in_sizes, int n_in,
                              void* d_out, int out_size, void* d_ws, size_t ws_size,
                              hipStream_t stream) {
  (void)in_sizes; (void)n_in; (void)out_size; (void)ws_size;
  const int*   lig_x       = (const int*)  d_in[0];
  const int*   rec_x_int   = (const int*)  d_in[1];
  const float* rec_x_float = (const float*)d_in[2];
  const int*   lig_ei      = (const int*)  d_in[3];
  const int*   rec_ei      = (const int*)  d_in[4];
  const int*   atom_off    = (const int*)  d_in[7];
  const float* atom_emb    = (const float*)d_in[8];
  const float* rec_emb1    = (const float*)d_in[9];
  const float* rec_w       = (const float*)d_in[10];
  const float* rec_b       = (const float*)d_in[11];
  const float* lig_W       = (const float*)d_in[12];
  const float* lig_gamma   = (const float*)d_in[14];
  const float* lig_beta    = (const float*)d_in[15];
  const float* rec_W       = (const float*)d_in[16];
  const float* rec_gamma   = (const float*)d_in[18];
  const float* rec_beta    = (const float*)d_in[19];
  const float* out_w1      = (const float*)d_in[20];
  const float* out_b1      = (const float*)d_in[21];
  const float* out_w2      = (const float*)d_in[22];
  const float* out_b2      = (const float*)d_in[23];
  float* out = (float*)d_out;

  char* p = (char*)d_ws;
  auto alloc = [&](size_t bytes) -> void* {
    void* r = p;
    p += (bytes + 255) & ~(size_t)255;
    return r;
  };
  ushort_t* Ab     = (ushort_t*)alloc((size_t)NREC * EMB * 2);  // features bf16
  ushort_t* Gb     = (ushort_t*)alloc((size_t)NREC * EMB * 2);  // g bf16
  ushort_t* Wtb    = (ushort_t*)alloc((size_t)EMB * EMB * 2);   // W^T bf16
  float* bnscl     = (float*)alloc(128 * 4);
  float* bnsh      = (float*)alloc(128 * 4);
  float* dinv_lig  = (float*)alloc((size_t)NLIG * 4);
  float* dinv_rec  = (float*)alloc((size_t)NREC * 4);
  int*   cnt_lig   = (int*)  alloc((size_t)NLIG * 4);
  int*   cnt_rec   = (int*)  alloc((size_t)NREC * 4);
  int*   off_lig   = (int*)  alloc((size_t)(NLIG + 1) * 4);
  int*   off_rec   = (int*)  alloc((size_t)(NREC + 1) * 4);
  int*   csr_lig   = (int*)  alloc((size_t)ELIG * 4);
  int*   csr_rec   = (int*)  alloc((size_t)EREC * 4);
  int*   bsum_lig  = (int*)  alloc(256 * 4);
  int*   bsum_rec  = (int*)  alloc(256 * 4);
  float* stats     = (float*)alloc(256 * 4);
  float* z         = (float*)alloc((size_t)NGRAPH * 256 * 4);

  // ---- CSR build ----
  hipMemsetAsync(cnt_lig, 0, (size_t)NLIG * 4, stream);
  hipMemsetAsync(cnt_rec, 0, (size_t)NREC * 4, stream);
  gk_count<<<ELIG / 256, 256, 0, stream>>>(lig_ei + ELIG, cnt_lig, ELIG);
  gk_count<<<EREC / 256, 256, 0, stream>>>(rec_ei + EREC, cnt_rec, EREC);
  gk_scan1<<<NLIG / 1024, 256, 0, stream>>>(cnt_lig, off_lig, bsum_lig, NLIG);
  gk_scan2<<<1, 256, 0, stream>>>(bsum_lig, NLIG / 1024);
  gk_scan3<<<NLIG / 256, 256, 0, stream>>>(off_lig, bsum_lig, NLIG, ELIG);
  gk_scan1<<<NREC / 1024, 256, 0, stream>>>(cnt_rec, off_rec, bsum_rec, NREC);
  gk_scan2<<<1, 256, 0, stream>>>(bsum_rec, NREC / 1024);
  gk_scan3<<<NREC / 256, 256, 0, stream>>>(off_rec, bsum_rec, NREC, EREC);
  gk_copy<<<NLIG / 256, 256, 0, stream>>>(cnt_lig, off_lig, NLIG);
  gk_copy<<<NREC / 256, 256, 0, stream>>>(cnt_rec, off_rec, NREC);
  gk_fill<<<ELIG / 256, 256, 0, stream>>>(lig_ei, lig_ei + ELIG, cnt_lig, csr_lig, ELIG);
  gk_fill<<<EREC / 256, 256, 0, stream>>>(rec_ei, rec_ei + EREC, cnt_rec, csr_rec, EREC);
  gk_dinv<<<NLIG / 256, 256, 0, stream>>>(off_lig, dinv_lig, NLIG);
  gk_dinv<<<NREC / 256, 256, 0, stream>>>(off_rec, dinv_rec, NREC);

  auto run_entity = [&](const float* Wall, const float* gamma, const float* beta,
                        const int* offv, const int* csrv, const float* dinv,
                        int n, int npg, int zoff) {
    float inv_n = 1.0f / (float)n;
    for (int l = 0; l < 3; ++l) {
      const float* W = Wall + (size_t)l * EMB * EMB;
      const float* gm = (l > 0) ? gamma + (size_t)(l - 1) * EMB : gamma;
      const float* bt = (l > 0) ? beta + (size_t)(l - 1) * EMB : beta;
      gk_prep<<<64, 256, 0, stream>>>(W, stats, gm, bt, inv_n, l > 0 ? 1 : 0,
                                      Wtb, bnscl, bnsh);
      hipMemsetAsync(stats, 0, 256 * 4, stream);
      gk_mm<<<n / 128, 256, 0, stream>>>(Ab, Wtb, bnscl, bnsh, l > 0 ? 1 : 0,
                                         dinv, Gb);
      gk_agg<<<n / 32, 256, 0, stream>>>(Gb, offv, csrv, dinv, Ab, stats);
    }
    gk_pool<<<NGRAPH, 128, 0, stream>>>(Ab, stats, gamma + 2 * EMB, beta + 2 * EMB,
                                        inv_n, z, npg, zoff);
  };

  // ---- ligand path ----
  gk_ligenc<<<NLIG, 128, 0, stream>>>(lig_x, atom_off, atom_emb, Ab);
  run_entity(lig_W, lig_gamma, lig_beta, off_lig, csr_lig, dinv_lig,
             NLIG, NLIG / NGRAPH, 0);

  // ---- receptor path ----
  gk_recenc<<<NREC / 64, 256, 0, stream>>>(rec_x_float, rec_x_int, rec_emb1,
                                           rec_w, rec_b, Ab);
  run_entity(rec_W, rec_gamma, rec_beta, off_rec, csr_rec, dinv_rec,
             NREC, NREC / NGRAPH, EMB);

  // ---- head ----
  gk_mlp<<<NGRAPH, 128, 0, stream>>>(z, out_w1, out_b1, out_w2, out_b2, out);
}